// Round 10
// baseline (314.216 us; speedup 1.0000x reference)
//
#include <hip/hip_runtime.h>
#include <stdint.h>

// MixHopNet, MI355X (gfx950). r16 verified 289.1us, absmax 0.03125.
// rocprof r16: all our kernels <42.9us (top-5 = harness 268MB reset fills).
// Post-mortem pair: r13's gemm "58us" was a profiling-replay artifact
// (r13 wall == r16 wall == 289); the only real wall regression was
// r14/r15 all-global weights (+38us). Lesson: wall for deltas, counters
// for signatures. Kernel-sum ~230 vs wall 289 -> ~60us launch gaps.
// gemm signature (r12): occ 17% (LDS 74240B -> 2 blocks/CU), Mfma 5%,
// latency-bound.
// r17: drop ONLY lW2 (21.8KB z-phase operand) -> LDS 52224B -> 3 blocks/CU
// (+50% waves). W2 z-phase reads go to the 61KB L2-hot wt2 (20x16B/thr/g,
// hidden by 12 waves/CU); hot h-phase lW stays in LDS (r15's lesson).
// lW2 removal also makes top-of-loop barrier removable (z-phase no longer
// reads restaged LDS): 2 barriers/g.
// Predicted: gemm LDS 52224, occ ~25%, dur ~33-38, BANK_CONFLICT -30%,
// wall ~282-285, absmax 0.03125. If regression -> LDS-weights strictly
// required; revert + pivot to launch fusion.

#define NODES 50000
#define NEDGE 800000
#define NSB   ((NODES + 255) / 256)   // 196

typedef __bf16 bf16x8 __attribute__((ext_vector_type(8)));
typedef float  floatx4 __attribute__((ext_vector_type(4)));
typedef float  floatx2 __attribute__((ext_vector_type(2)));

#if defined(__has_builtin)
#if __has_builtin(__builtin_amdgcn_cvt_pk_f32_fp8)
#define HW_FP8 1
#endif
#endif
#ifndef HW_FP8
#define HW_FP8 0
#endif

__device__ __forceinline__ float bf2f(unsigned short u) {
  unsigned int x = ((unsigned int)u) << 16;
  return __builtin_bit_cast(float, x);
}
__device__ __forceinline__ unsigned short f2bf(float f) {
  unsigned int x = __builtin_bit_cast(unsigned int, f);
  x += 0x7FFFu + ((x >> 16) & 1u);   // RNE
  return (unsigned short)(x >> 16);
}
__device__ __forceinline__ float ldf(const void* p, size_t i, int f32) {
  return f32 ? ((const float*)p)[i] : bf2f(((const unsigned short*)p)[i]);
}
__device__ __forceinline__ float fin(float x) { return __builtin_isfinite(x) ? x : 0.f; }
__device__ __forceinline__ uint4 pack8(const float* f) {
  float4 a = ((const float4*)f)[0], b = ((const float4*)f)[1];
  uint4 r;
  r.x = (unsigned)f2bf(a.x) | ((unsigned)f2bf(a.y) << 16);
  r.y = (unsigned)f2bf(a.z) | ((unsigned)f2bf(a.w) << 16);
  r.z = (unsigned)f2bf(b.x) | ((unsigned)f2bf(b.y) << 16);
  r.w = (unsigned)f2bf(b.z) | ((unsigned)f2bf(b.w) << 16);
  return r;
}

// ---- fp8 e4m3fn codec ----
__device__ __forceinline__ float fp8d(unsigned int b) {
  unsigned int bits = ((b & 0x80u) << 24) | ((b & 0x7Fu) << 20);
  return __builtin_bit_cast(float, bits) * __builtin_bit_cast(float, 0x7B800000u);
}
__device__ __forceinline__ floatx2 dec2(unsigned int u) {
#if HW_FP8
  return __builtin_amdgcn_cvt_pk_f32_fp8((int)u, false);
#else
  floatx2 r; r[0] = fp8d(u); r[1] = fp8d(u >> 8); return r;
#endif
}
__device__ __forceinline__ void dec8(uint2 q, float* v) {
#if HW_FP8
  floatx2 a = __builtin_amdgcn_cvt_pk_f32_fp8((int)q.x, false);
  floatx2 b = __builtin_amdgcn_cvt_pk_f32_fp8((int)q.x, true);
  floatx2 c = __builtin_amdgcn_cvt_pk_f32_fp8((int)q.y, false);
  floatx2 d = __builtin_amdgcn_cvt_pk_f32_fp8((int)q.y, true);
  v[0] = a[0]; v[1] = a[1]; v[2] = b[0]; v[3] = b[1];
  v[4] = c[0]; v[5] = c[1]; v[6] = d[0]; v[7] = d[1];
#else
  v[0] = fp8d(q.x);       v[1] = fp8d(q.x >> 8);
  v[2] = fp8d(q.x >> 16); v[3] = fp8d(q.x >> 24);
  v[4] = fp8d(q.y);       v[5] = fp8d(q.y >> 8);
  v[6] = fp8d(q.y >> 16); v[7] = fp8d(q.y >> 24);
#endif
}
// encode: clamp to +-448, f32->f16 RNE (hw), round mantissa 10->3 RNE with
// natural carry, rebias 15->7. |v| < 2^-6 flushes to signed zero.
__device__ __forceinline__ unsigned int fp8e(float f) {
  f = fminf(fmaxf(f, -448.f), 448.f);
  unsigned int u = (unsigned int)__builtin_bit_cast(unsigned short, (_Float16)f);
  unsigned int r = u + 0x3Fu + ((u >> 7) & 1u);
  unsigned int e5 = (r >> 10) & 0x1Fu;
  unsigned int sgn = (u >> 8) & 0x80u;
  unsigned int out = ((r >> 7) & 7u) | ((e5 - 8u) << 3) | sgn;
  return (e5 < 9u) ? sgn : out;
}
__device__ __forceinline__ void macc8q(uint2 q, float* a, float w) {
  float v[8];
  dec8(q, v);
  #pragma unroll
  for (int k = 0; k < 8; ++k) a[k] += w * v[k];
}

// ---------------- graph preprocessing ----------------

__global__ void k_count(const int* __restrict__ dst, int* __restrict__ cnt,
                        int* __restrict__ rank) {
  int e = blockIdx.x * blockDim.x + threadIdx.x;
  if (e < NEDGE) rank[e] = atomicAdd(&cnt[dst[e]], 1);
}

__global__ void k_scan_sum(const int* __restrict__ cnt, int* __restrict__ sums,
                           float* __restrict__ dinv,
                           const unsigned short* __restrict__ xs,
                           const unsigned short* __restrict__ ws_,
                           int* __restrict__ flags) {
  __shared__ int sdata[256];
  int t = threadIdx.x, idx = blockIdx.x * 256 + t;
  int c = (idx < NODES) ? cnt[idx] : 0;
  if (idx < NODES) dinv[idx] = rsqrtf((float)c + 1.0f);   // +1 self loop
  sdata[t] = c;
  __syncthreads();
  for (int off = 128; off; off >>= 1) {
    if (t < off) sdata[t] += sdata[t + off];
    __syncthreads();
  }
  if (t == 0) sums[blockIdx.x] = sdata[0];
  if (blockIdx.x == 0 && t < 64) {
    const unsigned short* ptrs[2] = {xs, ws_};
    for (int k = 0; k < 2; ++k) {
      int bad = 0;
      for (int i = 0; i < 4; ++i) {
        float v = bf2f(ptrs[k][t * 4 + i]);
        float a = fabsf(v);
        if (!(a <= 1e4f) || (v != 0.f && a < 1e-10f)) bad++;   // NaN fails a<=1e4
      }
      for (int off = 32; off; off >>= 1) bad += __shfl_xor(bad, off);
      if (t == 0) flags[k] = (bad > 16) ? 1 : 0;   // 1 = fp32
    }
  }
}

__global__ void k_scan_top(const int* __restrict__ sums, int* __restrict__ boff,
                           int* __restrict__ row_off) {
  __shared__ int sdata[256];
  int t = threadIdx.x;
  int v = (t < NSB) ? sums[t] : 0;
  int cur = v;
  sdata[t] = cur; __syncthreads();
  for (int off = 1; off < 256; off <<= 1) {
    int add = (t >= off) ? sdata[t - off] : 0;
    __syncthreads();
    cur += add; sdata[t] = cur;
    __syncthreads();
  }
  if (t < NSB) boff[t] = cur - v;           // exclusive
  if (t == NSB - 1) row_off[NODES] = cur;   // total == NEDGE
}

__global__ void k_scan_final(const int* __restrict__ cnt, const int* __restrict__ boff,
                             int* __restrict__ row_off) {
  __shared__ int sdata[256];
  int t = threadIdx.x, idx = blockIdx.x * 256 + t;
  int v = (idx < NODES) ? cnt[idx] : 0;
  int cur = v;
  sdata[t] = cur; __syncthreads();
  for (int off = 1; off < 256; off <<= 1) {
    int add = (t >= off) ? sdata[t - off] : 0;
    __syncthreads();
    cur += add; sdata[t] = cur;
    __syncthreads();
  }
  if (idx < NODES) row_off[idx] = boff[blockIdx.x] + cur - v;
}

#define FILL_BLOCKS (NEDGE / 256)   // 3125

// r12: no atomics; pos = row_off[d] + rank[e].
__global__ void k_fill_prep(const int* __restrict__ src, const int* __restrict__ dst,
                            const int* __restrict__ row_off, const int* __restrict__ rank,
                            const float* __restrict__ dinv, unsigned int* __restrict__ edges,
                            const void* __restrict__ w1_0, const void* __restrict__ w1_1,
                            const void* __restrict__ w1_2, const void* __restrict__ w2_0,
                            const void* __restrict__ w2_1, const int* __restrict__ flags,
                            unsigned short* __restrict__ wt1, unsigned short* __restrict__ wt2) {
  if (blockIdx.x < FILL_BLOCKS) {
    int e = blockIdx.x * 256 + threadIdx.x;
    int s = src[e], d = dst[e];
    int pos = row_off[d] + rank[e];
    float w = dinv[s] * dinv[d];
    _Float16 hw = (_Float16)w;
    edges[pos] = ((unsigned int)__builtin_bit_cast(unsigned short, hw) << 16)
               | (unsigned int)(s & 0xFFFF);
  } else {
    int fw = flags[1];
    int idx = (blockIdx.x - FILL_BLOCKS) * 256 + threadIdx.x;
    if (idx < 3 * 128 * 128) {
      int g = idx / 16384, r = idx % 16384;
      int n = r / 128, k = r % 128;
      const void* w = (g == 0) ? w1_0 : (g == 1) ? w1_1 : w1_2;
      wt1[idx] = f2bf(ldf(w, (size_t)k * 128 + n, fw));
    } else {
      int r = idx - 49152;   // 312*256 - 49152 = 30720 = 80*384 exactly
      int n = r / 384, k = r % 384;
      float v = (n < 40) ? ldf(w2_0, (size_t)k * 40 + n, fw)
                         : ldf(w2_1, (size_t)k * 40 + (n - 40), fw);
      wt2[r] = f2bf(v);
    }
  }
}

__device__ __forceinline__ void unpack_edge(unsigned int e, int& s, float& w) {
  s = (int)(e & 0xFFFFu);
  w = (float)__builtin_bit_cast(_Float16, (unsigned short)(e >> 16));
}

// ---------------- x -> fp8 quantize (r10) ----------------
__global__ __launch_bounds__(256) void k_quant_x(const void* __restrict__ x,
                                                 unsigned char* __restrict__ xq,
                                                 const int* __restrict__ flags) {
  int f32 = flags[0];
  size_t i = ((size_t)blockIdx.x * 256 + threadIdx.x) * 8;
  float v[8];
  if (f32) {
    const float* xf = (const float*)x;
    #pragma unroll
    for (int k = 0; k < 8; ++k) v[k] = xf[i + k];
  } else {
    uint4 q = *(const uint4*)((const unsigned short*)x + i);
    v[0] = bf2f((unsigned short)(q.x & 0xFFFF));
    v[1] = bf2f((unsigned short)(q.x >> 16));
    v[2] = bf2f((unsigned short)(q.y & 0xFFFF));
    v[3] = bf2f((unsigned short)(q.y >> 16));
    v[4] = bf2f((unsigned short)(q.z & 0xFFFF));
    v[5] = bf2f((unsigned short)(q.z >> 16));
    v[6] = bf2f((unsigned short)(q.w & 0xFFFF));
    v[7] = bf2f((unsigned short)(q.w >> 16));
  }
  uint2 o;
  o.x = fp8e(v[0]) | (fp8e(v[1]) << 8) | (fp8e(v[2]) << 16) | (fp8e(v[3]) << 24);
  o.y = fp8e(v[4]) | (fp8e(v[5]) << 8) | (fp8e(v[6]) << 16) | (fp8e(v[7]) << 24);
  *(uint2*)(xq + i) = o;
}

// ---------------- z1 bf16 -> fp8 quantize (r16) ----------------
__global__ __launch_bounds__(256) void k_quant_z(const unsigned short* __restrict__ z1,
                                                 unsigned char* __restrict__ z1q) {
  int idx = blockIdx.x * 256 + threadIdx.x;
  if (idx >= NODES * 40 / 8) return;
  size_t i = (size_t)idx * 8;
  uint4 q = *(const uint4*)(z1 + i);
  uint2 o;
  o.x = fp8e(bf2f((unsigned short)(q.x & 0xFFFF)))
      | (fp8e(bf2f((unsigned short)(q.x >> 16))) << 8)
      | (fp8e(bf2f((unsigned short)(q.y & 0xFFFF))) << 16)
      | (fp8e(bf2f((unsigned short)(q.y >> 16))) << 24);
  o.y = fp8e(bf2f((unsigned short)(q.z & 0xFFFF)))
      | (fp8e(bf2f((unsigned short)(q.z >> 16))) << 8)
      | (fp8e(bf2f((unsigned short)(q.w & 0xFFFF))) << 16)
      | (fp8e(bf2f((unsigned short)(q.w >> 16))) << 24);
  *(uint2*)(z1q + i) = o;
}

// ---------------- 128-wide propagate, fp8 gather ----------------
__global__ __launch_bounds__(256) void k_prop128(
    const unsigned char* __restrict__ inq, void* __restrict__ outp,
    const int* __restrict__ row_off, const unsigned int* __restrict__ edges,
    const float* __restrict__ dinv, int out_fp8) {
  int v = blockIdx.x * 4 + (threadIdx.x >> 6);
  if (v >= NODES) return;
  int lane = threadIdx.x & 63;
  int rb = row_off[v], re = row_off[v + 1];
  float dv = dinv[v];
  float wsw = dv * dv;
  int slot = lane >> 4, fl = lane & 15;
  float acc[8], acc2[8];
  {
    uint2 q = *(const uint2*)(inq + (size_t)v * 128 + fl * 8);
    float sw = (slot == 0) ? wsw : 0.f;
    float v8[8];
    dec8(q, v8);
    #pragma unroll
    for (int k = 0; k < 8; ++k) { acc[k] = sw * v8[k]; acc2[k] = 0.f; }
  }
  int j = rb + slot;
  for (; j + 4 < re; j += 8) {
    int s1; float w1; unpack_edge(edges[j], s1, w1);
    int s2; float w2; unpack_edge(edges[j + 4], s2, w2);
    uint2 q1 = *(const uint2*)(inq + (size_t)s1 * 128 + fl * 8);
    uint2 q2 = *(const uint2*)(inq + (size_t)s2 * 128 + fl * 8);
    macc8q(q1, acc, w1);
    macc8q(q2, acc2, w2);
  }
  if (j < re) {
    int s; float w; unpack_edge(edges[j], s, w);
    uint2 q = *(const uint2*)(inq + (size_t)s * 128 + fl * 8);
    macc8q(q, acc, w);
  }
  #pragma unroll
  for (int k = 0; k < 8; ++k) acc[k] += acc2[k];
  #pragma unroll
  for (int k = 0; k < 8; ++k) {
    acc[k] += __shfl_xor(acc[k], 32);
    acc[k] += __shfl_xor(acc[k], 16);
  }
  if (slot == 0) {
    #pragma unroll
    for (int k = 0; k < 8; ++k) acc[k] = fin(acc[k]);
    if (out_fp8) {
      uint2 o;
      o.x = fp8e(acc[0]) | (fp8e(acc[1]) << 8) | (fp8e(acc[2]) << 16) | (fp8e(acc[3]) << 24);
      o.y = fp8e(acc[4]) | (fp8e(acc[5]) << 8) | (fp8e(acc[6]) << 16) | (fp8e(acc[7]) << 24);
      *(uint2*)((unsigned char*)outp + (size_t)v * 128 + fl * 8) = o;
    } else {
      uint4 o = pack8(acc);
      *(uint4*)((unsigned short*)outp + (size_t)v * 128 + fl * 8) = o;
    }
  }
}

// ---------------- fused conv1+conv2 ----------------
// r17: lW (h-phase W1) stays in LDS; lW2 DROPPED (z-phase W2 fragments
// read direct from 61KB L2-hot wt2). lA kept. 2 barriers per g (top
// barrier removable: staging writes lW only, z-phase reads lA+global).
// z1 stored bf16 (r16); quant_z converts after.
__global__ __launch_bounds__(256) void k_gemm_fused(
    const void* __restrict__ x, const unsigned char* __restrict__ x1q,
    const unsigned short* __restrict__ x2, const unsigned short* __restrict__ wt1,
    const unsigned short* __restrict__ wt2,
    const unsigned short* __restrict__ b0, const unsigned short* __restrict__ b1,
    const unsigned short* __restrict__ b2, void* __restrict__ outp,
    unsigned short* __restrict__ z1, const int* __restrict__ flags) {
  __shared__ unsigned short lA[64 * 136];    // h tile
  __shared__ unsigned short lW[128 * 136];   // W1_g [n][k]
  int f32x = flags[0];
  int m0 = blockIdx.x * 64;
  int t = threadIdx.x;
  int wave = t >> 6, lane = t & 63;
  int lr = lane & 15, lq = lane >> 4;
  int wr = (wave >> 1) * 32, wc = (wave & 1) * 64;
  floatx4 zacc[5] = {};

  for (int g = 0; g < 3; ++g) {
    const unsigned short* Ab = (g == 0) ? (const unsigned short*)x : x2;
    const unsigned short* W = wt1 + g * 16384;
    const unsigned short* bias = (g == 0) ? b0 : (g == 1) ? b1 : b2;
    // stage lW. Safe without a preceding barrier: prior-g h-phase lW reads
    // finished before the pre-z barrier; prior-g z-phase reads only lA +
    // global wt2, never lW.
    for (int i = 0; i < 8; ++i) {            // W1: 128 x 16 chunks
      int idx = t + i * 256;
      int row = idx >> 4, c16 = idx & 15;
      *(uint4*)(&lW[row * 136 + c16 * 8]) =
          *(const uint4*)(W + row * 128 + c16 * 8);
    }
    __syncthreads();   // staging done; also implies all waves left prior z-phase

    // h-phase: A fragments straight from global, W1 from LDS
    floatx4 acc[2][4] = {};
    for (int ks = 0; ks < 4; ++ks) {
      int k0 = ks * 32 + lq * 8;
      bf16x8 af[2], bfr[4];
      for (int i = 0; i < 2; ++i) {
        int gr = m0 + wr + i * 16 + lr;
        if (gr < NODES) {
          if (g == 1) {
            uint2 qq = *(const uint2*)(x1q + (size_t)gr * 128 + k0);
            float tv[8];
            dec8(qq, tv);
            uint4 t4 = pack8(tv);
            af[i] = __builtin_bit_cast(bf16x8, t4);
          } else if (g == 0 && f32x) {
            uint4 t4 = pack8((const float*)x + (size_t)gr * 128 + k0);
            af[i] = __builtin_bit_cast(bf16x8, t4);
          } else {
            af[i] = *(const bf16x8*)(Ab + (size_t)gr * 128 + k0);
          }
        } else {
          uint4 zz = {0, 0, 0, 0};
          af[i] = __builtin_bit_cast(bf16x8, zz);
        }
      }
      for (int j = 0; j < 4; ++j)
        bfr[j] = *(const bf16x8*)(&lW[(wc + j * 16 + lr) * 136 + k0]);
      for (int i = 0; i < 2; ++i)
        for (int j = 0; j < 4; ++j)
          acc[i][j] = __builtin_amdgcn_mfma_f32_16x16x32_bf16(af[i], bfr[j], acc[i][j], 0, 0, 0);
    }
    // h -> LDS (prior z-phase lA reads done: all waves passed the staging
    // barrier after their z-phase)
    for (int i = 0; i < 2; ++i) {
      int rloc = wr + i * 16 + lq * 4;
      for (int j = 0; j < 4; ++j) {
        int col = wc + j * 16 + lr;
        float bv = bf2f(bias[col]);
        for (int r = 0; r < 4; ++r) {
          float val = acc[i][j][r] + bv;
          val = val > 0.f ? val : 0.f;       // relu (squashes NaN too)
          lA[(rloc + r) * 136 + col] = f2bf(val);
        }
      }
    }
    __syncthreads();
    // z-phase: h from lA, W2 fragments direct from global (L2-hot)
    for (int ks = 0; ks < 4; ++ks) {
      int k0 = ks * 32 + lq * 8;
      bf16x8 ah = *(const bf16x8*)(&lA[(wave * 16 + lr) * 136 + k0]);
      bf16x8 bw[5];
      for (int j = 0; j < 5; ++j)
        bw[j] = *(const bf16x8*)(wt2 + (j * 16 + lr) * 384 + g * 128 + k0);
      for (int j = 0; j < 5; ++j)
        zacc[j] = __builtin_amdgcn_mfma_f32_16x16x32_bf16(ah, bw[j], zacc[j], 0, 0, 0);
    }
  }
  int rbase = m0 + wave * 16 + lq * 4;
  for (int j = 0; j < 5; ++j) {
    int col = j * 16 + lr;
    for (int r = 0; r < 4; ++r) {
      int gr = rbase + r;
      if (gr < NODES) {
        float vv = zacc[j][r];
        if (col < 40) {
          if (f32x) ((float*)outp)[(size_t)gr * 80 + col] = vv;
          else ((unsigned short*)outp)[(size_t)gr * 80 + col] = f2bf(vv);
        } else {
          z1[(size_t)gr * 40 + (col - 40)] = f2bf(vv);
        }
      }
    }
  }
}

// ---------------- fused 40-d propagate + bias + log_softmax ----------------
// r13: z1 rows are fp8 (40B); each lane loads ushort = 2 fp8, 1 cvt_pk.
__global__ __launch_bounds__(256) void k_prop40_softmax(
    const unsigned char* __restrict__ z1q, const unsigned short* __restrict__ b2_0,
    const unsigned short* __restrict__ b2_1, const int* __restrict__ row_off,
    const unsigned int* __restrict__ edges, const float* __restrict__ dinv,
    void* __restrict__ outp, const int* __restrict__ flags) {
  int f32o = flags[0];
  int v = blockIdx.x * 4 + (threadIdx.x >> 6);
  if (v >= NODES) return;
  int lane = threadIdx.x & 63;
  int slot = lane >> 5, fl = lane & 31;
  bool gact = fl < 20;
  int fo = gact ? fl * 2 : 0;
  int rb = row_off[v], re = row_off[v + 1];
  float dv = dinv[v];
  float wsw = dv * dv;
  float ax = 0.f, ay = 0.f, bx = 0.f, by = 0.f;
  if (slot == 0) {
    unsigned int p = *(const unsigned short*)(z1q + (size_t)v * 40 + fo);
    floatx2 d = dec2(p);
    ax = wsw * d[0];
    ay = wsw * d[1];
  }
  int j = rb + slot;
  for (; j + 2 < re; j += 4) {   // two stride-2 steps per iteration
    int s1; float w1; unpack_edge(edges[j], s1, w1);
    int s2; float w2; unpack_edge(edges[j + 2], s2, w2);
    unsigned int q1 = *(const unsigned short*)(z1q + (size_t)s1 * 40 + fo);
    unsigned int q2 = *(const unsigned short*)(z1q + (size_t)s2 * 40 + fo);
    floatx2 d1 = dec2(q1);
    floatx2 d2 = dec2(q2);
    ax += w1 * d1[0];
    ay += w1 * d1[1];
    bx += w2 * d2[0];
    by += w2 * d2[1];
  }
  if (j < re) {
    int s; float w; unpack_edge(edges[j], s, w);
    unsigned int q = *(const unsigned short*)(z1q + (size_t)s * 40 + fo);
    floatx2 d = dec2(q);
    ax += w * d[0];
    ay += w * d[1];
  }
  ax += bx; ay += by;
  ax += __shfl_xor(ax, 32);
  ay += __shfl_xor(ay, 32);
  bool act = lane < 20;
  float l0x = 0.f, l0y = 0.f, l1x = 0.f, l1y = 0.f;
  if (act) {
    l0x = fin(ldf(outp, (size_t)v * 80 + fo, f32o)     + bf2f(b2_0[fo]));
    l0y = fin(ldf(outp, (size_t)v * 80 + fo + 1, f32o) + bf2f(b2_0[fo + 1]));
    l1x = fin(ax + bf2f(b2_1[fo]));
    l1y = fin(ay + bf2f(b2_1[fo + 1]));
  }
  float m = act ? fmaxf(fmaxf(l0x, l0y), fmaxf(l1x, l1y)) : -INFINITY;
  for (int off = 32; off; off >>= 1) m = fmaxf(m, __shfl_xor(m, off));
  float s = act ? (expf(l0x - m) + expf(l0y - m) + expf(l1x - m) + expf(l1y - m)) : 0.f;
  for (int off = 32; off; off >>= 1) s += __shfl_xor(s, off);
  float lse = m + logf(s);
  if (act) {
    if (f32o) {
      float* of = (float*)outp;
      of[(size_t)v * 80 + fo]          = l0x - lse;
      of[(size_t)v * 80 + fo + 1]      = l0y - lse;
      of[(size_t)v * 80 + 40 + fo]     = l1x - lse;
      of[(size_t)v * 80 + 40 + fo + 1] = l1y - lse;
    } else {
      unsigned short* ob = (unsigned short*)outp;
      unsigned int o0 = ((unsigned int)f2bf(l0y - lse) << 16) | f2bf(l0x - lse);
      unsigned int o1 = ((unsigned int)f2bf(l1y - lse) << 16) | f2bf(l1x - lse);
      *(unsigned int*)(ob + (size_t)v * 80 + fo) = o0;
      *(unsigned int*)(ob + (size_t)v * 80 + 40 + fo) = o1;
    }
  }
}

// sentinel: ws too small — encode its MB count into the output
__global__ void k_sentinel(unsigned short* o, int n, float val) {
  int i = blockIdx.x * blockDim.x + threadIdx.x;
  if (i < n) o[i] = f2bf(val);
}

// ---------------- host ----------------

static inline size_t al256(size_t x) { return (x + 255) & ~(size_t)255; }

extern "C" void kernel_launch(void* const* d_in, const int* in_sizes, int n_in,
                              void* d_out, int out_size, void* d_ws, size_t ws_size,
                              hipStream_t stream) {
  const void* x    = d_in[0];
  const int*  ei   = (const int*)d_in[1];
  const void* w1_0 = d_in[2];
  const unsigned short* b1_0 = (const unsigned short*)d_in[3];
  const void* w1_1 = d_in[4];
  const unsigned short* b1_1 = (const unsigned short*)d_in[5];
  const void* w1_2 = d_in[6];
  const unsigned short* b1_2 = (const unsigned short*)d_in[7];
  const void* w2_0 = d_in[8];
  const unsigned short* b2_0 = (const unsigned short*)d_in[9];
  const void* w2_1 = d_in[10];
  const unsigned short* b2_1 = (const unsigned short*)d_in[11];
  const int* srcv = ei;
  const int* dstv = ei + NEDGE;

  // ws layout: same 33.8 MB total as r4-r16. z1 slot holds bf16 z1 (4MB).
  // rank[] AND z1q both alias the x2v slot at disjoint times:
  // rank (count/fill, early) -> x2v (prop128-pass2..gemm) -> z1q (quant_z..prop40).
  char* p = (char*)d_ws;
  int*   flags   = (int*)p;               p += al256(2 * 4);
  int*   row_off = (int*)p;               p += al256((NODES + 1) * 4);
  float* dinv    = (float*)p;             p += al256(NODES * 4);
  unsigned int* edges = (unsigned int*)p; p += al256((size_t)NEDGE * 4);
  unsigned short* wt1 = (unsigned short*)p; p += al256(3 * 128 * 128 * 2);
  unsigned short* wt2 = (unsigned short*)p; p += al256(80 * 384 * 2);
  unsigned char* xq  = (unsigned char*)p; p += al256((size_t)NODES * 128);
  unsigned char* x1q = (unsigned char*)p; p += al256((size_t)NODES * 128);
  unsigned short* x2v = (unsigned short*)p; p += al256((size_t)NODES * 128 * 2);
  unsigned short* z1 = (unsigned short*)p; p += al256((size_t)NODES * 40 * 2);
  int*   cnt     = (int*)p;               p += al256(NODES * 4);
  int*   cursor  = (int*)p;               p += al256(NODES * 4);
  int*   sums    = (int*)p;               p += al256(NSB * 4);
  int*   boff    = (int*)p;               p += al256(NSB * 4);
  size_t need = (size_t)(p - (char*)d_ws);
  int* rank = (int*)x2v;                 // early alias of x2v slot
  unsigned char* z1q = (unsigned char*)x2v;  // late alias (x2v dead post-gemm)
  (void)cursor;

  if (ws_size < need) {
    float val = -1000.f - (float)(ws_size >> 20);
    k_sentinel<<<(out_size + 255) / 256, 256, 0, stream>>>(
        (unsigned short*)d_out, out_size, val);
    return;
  }

  hipMemsetAsync(cnt, 0, al256(NODES * 4) + NODES * 4, stream);
  k_count<<<NEDGE / 256, 256, 0, stream>>>(dstv, cnt, rank);
  k_scan_sum<<<NSB, 256, 0, stream>>>(cnt, sums, dinv,
                                      (const unsigned short*)x,
                                      (const unsigned short*)w1_0, flags);
  k_scan_top<<<1, 256, 0, stream>>>(sums, boff, row_off);
  k_scan_final<<<NSB, 256, 0, stream>>>(cnt, boff, row_off);
  k_quant_x<<<(NODES * 128 / 8) / 256, 256, 0, stream>>>(x, xq, flags);
  k_fill_prep<<<FILL_BLOCKS + 312, 256, 0, stream>>>(
      srcv, dstv, row_off, rank, dinv, edges,
      w1_0, w1_1, w1_2, w2_0, w2_1, flags, wt1, wt2);
  k_prop128<<<NODES / 4, 256, 0, stream>>>(xq, x1q, row_off, edges, dinv, 1);
  k_prop128<<<NODES / 4, 256, 0, stream>>>(x1q, x2v, row_off, edges, dinv, 0);
  k_gemm_fused<<<(NODES + 63) / 64, 256, 0, stream>>>(x, x1q, x2v, wt1, wt2,
                                                      b1_0, b1_1, b1_2, d_out, z1, flags);
  k_quant_z<<<(NODES * 40 / 8 + 255) / 256, 256, 0, stream>>>(z1, z1q);
  k_prop40_softmax<<<NODES / 4, 256, 0, stream>>>(z1q, b2_0, b2_1, row_off, edges,
                                                  dinv, d_out, flags);
}

// Round 12
// 284.879 us; speedup vs baseline: 1.1030x; 1.1030x over previous
//
#include <hip/hip_runtime.h>
#include <stdint.h>

// MixHopNet, MI355X (gfx950). r17 FAILED: wall 289->314. LDS 52224 +
// conflicts halved as predicted, but occ only 17->20% and gemm 60us -
// z-phase global W2 reads on the latency-bound critical path (same
// mechanism as r15). CLOSED: both weight operands stay in LDS; gemm
// (~40us, occ 17%, Mfma 5%) resists occupancy levers - stop touching it.
// r18 = r16 verbatim (verified 289.1, session best) EXCEPT prop128/prop40
// edge-word software prefetch: load iteration i+1's 2 edge words BEFORE
// iteration i's gathers (edge L2 latency ~150-200cy hides under gathers).
// Accumulation order bitwise-identical to r16 -> absmax must be 0.03125.
// Predicted: prop128 ~35->~28-30 each, prop40 ~30->~26, FETCH unchanged,
// wall ~272-278. If flat -> edge loads already hidden; props are at the
// gather-latency floor and we're near this family's ceiling.
// r19 == r18 resubmitted verbatim: previous bench was an infra failure
// (container died twice; precedent r8/r15 both passed clean on resubmit).

#define NODES 50000
#define NEDGE 800000
#define NSB   ((NODES + 255) / 256)   // 196

typedef __bf16 bf16x8 __attribute__((ext_vector_type(8)));
typedef float  floatx4 __attribute__((ext_vector_type(4)));
typedef float  floatx2 __attribute__((ext_vector_type(2)));

#if defined(__has_builtin)
#if __has_builtin(__builtin_amdgcn_cvt_pk_f32_fp8)
#define HW_FP8 1
#endif
#endif
#ifndef HW_FP8
#define HW_FP8 0
#endif

__device__ __forceinline__ float bf2f(unsigned short u) {
  unsigned int x = ((unsigned int)u) << 16;
  return __builtin_bit_cast(float, x);
}
__device__ __forceinline__ unsigned short f2bf(float f) {
  unsigned int x = __builtin_bit_cast(unsigned int, f);
  x += 0x7FFFu + ((x >> 16) & 1u);   // RNE
  return (unsigned short)(x >> 16);
}
__device__ __forceinline__ float ldf(const void* p, size_t i, int f32) {
  return f32 ? ((const float*)p)[i] : bf2f(((const unsigned short*)p)[i]);
}
__device__ __forceinline__ float fin(float x) { return __builtin_isfinite(x) ? x : 0.f; }
__device__ __forceinline__ uint4 pack8(const float* f) {
  float4 a = ((const float4*)f)[0], b = ((const float4*)f)[1];
  uint4 r;
  r.x = (unsigned)f2bf(a.x) | ((unsigned)f2bf(a.y) << 16);
  r.y = (unsigned)f2bf(a.z) | ((unsigned)f2bf(a.w) << 16);
  r.z = (unsigned)f2bf(b.x) | ((unsigned)f2bf(b.y) << 16);
  r.w = (unsigned)f2bf(b.z) | ((unsigned)f2bf(b.w) << 16);
  return r;
}

// ---- fp8 e4m3fn codec ----
__device__ __forceinline__ float fp8d(unsigned int b) {
  unsigned int bits = ((b & 0x80u) << 24) | ((b & 0x7Fu) << 20);
  return __builtin_bit_cast(float, bits) * __builtin_bit_cast(float, 0x7B800000u);
}
__device__ __forceinline__ floatx2 dec2(unsigned int u) {
#if HW_FP8
  return __builtin_amdgcn_cvt_pk_f32_fp8((int)u, false);
#else
  floatx2 r; r[0] = fp8d(u); r[1] = fp8d(u >> 8); return r;
#endif
}
__device__ __forceinline__ void dec8(uint2 q, float* v) {
#if HW_FP8
  floatx2 a = __builtin_amdgcn_cvt_pk_f32_fp8((int)q.x, false);
  floatx2 b = __builtin_amdgcn_cvt_pk_f32_fp8((int)q.x, true);
  floatx2 c = __builtin_amdgcn_cvt_pk_f32_fp8((int)q.y, false);
  floatx2 d = __builtin_amdgcn_cvt_pk_f32_fp8((int)q.y, true);
  v[0] = a[0]; v[1] = a[1]; v[2] = b[0]; v[3] = b[1];
  v[4] = c[0]; v[5] = c[1]; v[6] = d[0]; v[7] = d[1];
#else
  v[0] = fp8d(q.x);       v[1] = fp8d(q.x >> 8);
  v[2] = fp8d(q.x >> 16); v[3] = fp8d(q.x >> 24);
  v[4] = fp8d(q.y);       v[5] = fp8d(q.y >> 8);
  v[6] = fp8d(q.y >> 16); v[7] = fp8d(q.y >> 24);
#endif
}
// encode: clamp to +-448, f32->f16 RNE (hw), round mantissa 10->3 RNE with
// natural carry, rebias 15->7. |v| < 2^-6 flushes to signed zero.
__device__ __forceinline__ unsigned int fp8e(float f) {
  f = fminf(fmaxf(f, -448.f), 448.f);
  unsigned int u = (unsigned int)__builtin_bit_cast(unsigned short, (_Float16)f);
  unsigned int r = u + 0x3Fu + ((u >> 7) & 1u);
  unsigned int e5 = (r >> 10) & 0x1Fu;
  unsigned int sgn = (u >> 8) & 0x80u;
  unsigned int out = ((r >> 7) & 7u) | ((e5 - 8u) << 3) | sgn;
  return (e5 < 9u) ? sgn : out;
}
__device__ __forceinline__ void macc8q(uint2 q, float* a, float w) {
  float v[8];
  dec8(q, v);
  #pragma unroll
  for (int k = 0; k < 8; ++k) a[k] += w * v[k];
}

// ---------------- graph preprocessing ----------------

__global__ void k_count(const int* __restrict__ dst, int* __restrict__ cnt,
                        int* __restrict__ rank) {
  int e = blockIdx.x * blockDim.x + threadIdx.x;
  if (e < NEDGE) rank[e] = atomicAdd(&cnt[dst[e]], 1);
}

__global__ void k_scan_sum(const int* __restrict__ cnt, int* __restrict__ sums,
                           float* __restrict__ dinv,
                           const unsigned short* __restrict__ xs,
                           const unsigned short* __restrict__ ws_,
                           int* __restrict__ flags) {
  __shared__ int sdata[256];
  int t = threadIdx.x, idx = blockIdx.x * 256 + t;
  int c = (idx < NODES) ? cnt[idx] : 0;
  if (idx < NODES) dinv[idx] = rsqrtf((float)c + 1.0f);   // +1 self loop
  sdata[t] = c;
  __syncthreads();
  for (int off = 128; off; off >>= 1) {
    if (t < off) sdata[t] += sdata[t + off];
    __syncthreads();
  }
  if (t == 0) sums[blockIdx.x] = sdata[0];
  if (blockIdx.x == 0 && t < 64) {
    const unsigned short* ptrs[2] = {xs, ws_};
    for (int k = 0; k < 2; ++k) {
      int bad = 0;
      for (int i = 0; i < 4; ++i) {
        float v = bf2f(ptrs[k][t * 4 + i]);
        float a = fabsf(v);
        if (!(a <= 1e4f) || (v != 0.f && a < 1e-10f)) bad++;   // NaN fails a<=1e4
      }
      for (int off = 32; off; off >>= 1) bad += __shfl_xor(bad, off);
      if (t == 0) flags[k] = (bad > 16) ? 1 : 0;   // 1 = fp32
    }
  }
}

__global__ void k_scan_top(const int* __restrict__ sums, int* __restrict__ boff,
                           int* __restrict__ row_off) {
  __shared__ int sdata[256];
  int t = threadIdx.x;
  int v = (t < NSB) ? sums[t] : 0;
  int cur = v;
  sdata[t] = cur; __syncthreads();
  for (int off = 1; off < 256; off <<= 1) {
    int add = (t >= off) ? sdata[t - off] : 0;
    __syncthreads();
    cur += add; sdata[t] = cur;
    __syncthreads();
  }
  if (t < NSB) boff[t] = cur - v;           // exclusive
  if (t == NSB - 1) row_off[NODES] = cur;   // total == NEDGE
}

__global__ void k_scan_final(const int* __restrict__ cnt, const int* __restrict__ boff,
                             int* __restrict__ row_off) {
  __shared__ int sdata[256];
  int t = threadIdx.x, idx = blockIdx.x * 256 + t;
  int v = (idx < NODES) ? cnt[idx] : 0;
  int cur = v;
  sdata[t] = cur; __syncthreads();
  for (int off = 1; off < 256; off <<= 1) {
    int add = (t >= off) ? sdata[t - off] : 0;
    __syncthreads();
    cur += add; sdata[t] = cur;
    __syncthreads();
  }
  if (idx < NODES) row_off[idx] = boff[blockIdx.x] + cur - v;
}

#define FILL_BLOCKS (NEDGE / 256)   // 3125

// r12: no atomics; pos = row_off[d] + rank[e].
__global__ void k_fill_prep(const int* __restrict__ src, const int* __restrict__ dst,
                            const int* __restrict__ row_off, const int* __restrict__ rank,
                            const float* __restrict__ dinv, unsigned int* __restrict__ edges,
                            const void* __restrict__ w1_0, const void* __restrict__ w1_1,
                            const void* __restrict__ w1_2, const void* __restrict__ w2_0,
                            const void* __restrict__ w2_1, const int* __restrict__ flags,
                            unsigned short* __restrict__ wt1, unsigned short* __restrict__ wt2) {
  if (blockIdx.x < FILL_BLOCKS) {
    int e = blockIdx.x * 256 + threadIdx.x;
    int s = src[e], d = dst[e];
    int pos = row_off[d] + rank[e];
    float w = dinv[s] * dinv[d];
    _Float16 hw = (_Float16)w;
    edges[pos] = ((unsigned int)__builtin_bit_cast(unsigned short, hw) << 16)
               | (unsigned int)(s & 0xFFFF);
  } else {
    int fw = flags[1];
    int idx = (blockIdx.x - FILL_BLOCKS) * 256 + threadIdx.x;
    if (idx < 3 * 128 * 128) {
      int g = idx / 16384, r = idx % 16384;
      int n = r / 128, k = r % 128;
      const void* w = (g == 0) ? w1_0 : (g == 1) ? w1_1 : w1_2;
      wt1[idx] = f2bf(ldf(w, (size_t)k * 128 + n, fw));
    } else {
      int r = idx - 49152;   // 312*256 - 49152 = 30720 = 80*384 exactly
      int n = r / 384, k = r % 384;
      float v = (n < 40) ? ldf(w2_0, (size_t)k * 40 + n, fw)
                         : ldf(w2_1, (size_t)k * 40 + (n - 40), fw);
      wt2[r] = f2bf(v);
    }
  }
}

__device__ __forceinline__ void unpack_edge(unsigned int e, int& s, float& w) {
  s = (int)(e & 0xFFFFu);
  w = (float)__builtin_bit_cast(_Float16, (unsigned short)(e >> 16));
}

// ---------------- x -> fp8 quantize (r10) ----------------
__global__ __launch_bounds__(256) void k_quant_x(const void* __restrict__ x,
                                                 unsigned char* __restrict__ xq,
                                                 const int* __restrict__ flags) {
  int f32 = flags[0];
  size_t i = ((size_t)blockIdx.x * 256 + threadIdx.x) * 8;
  float v[8];
  if (f32) {
    const float* xf = (const float*)x;
    #pragma unroll
    for (int k = 0; k < 8; ++k) v[k] = xf[i + k];
  } else {
    uint4 q = *(const uint4*)((const unsigned short*)x + i);
    v[0] = bf2f((unsigned short)(q.x & 0xFFFF));
    v[1] = bf2f((unsigned short)(q.x >> 16));
    v[2] = bf2f((unsigned short)(q.y & 0xFFFF));
    v[3] = bf2f((unsigned short)(q.y >> 16));
    v[4] = bf2f((unsigned short)(q.z & 0xFFFF));
    v[5] = bf2f((unsigned short)(q.z >> 16));
    v[6] = bf2f((unsigned short)(q.w & 0xFFFF));
    v[7] = bf2f((unsigned short)(q.w >> 16));
  }
  uint2 o;
  o.x = fp8e(v[0]) | (fp8e(v[1]) << 8) | (fp8e(v[2]) << 16) | (fp8e(v[3]) << 24);
  o.y = fp8e(v[4]) | (fp8e(v[5]) << 8) | (fp8e(v[6]) << 16) | (fp8e(v[7]) << 24);
  *(uint2*)(xq + i) = o;
}

// ---------------- z1 bf16 -> fp8 quantize (r16) ----------------
__global__ __launch_bounds__(256) void k_quant_z(const unsigned short* __restrict__ z1,
                                                 unsigned char* __restrict__ z1q) {
  int idx = blockIdx.x * 256 + threadIdx.x;
  if (idx >= NODES * 40 / 8) return;
  size_t i = (size_t)idx * 8;
  uint4 q = *(const uint4*)(z1 + i);
  uint2 o;
  o.x = fp8e(bf2f((unsigned short)(q.x & 0xFFFF)))
      | (fp8e(bf2f((unsigned short)(q.x >> 16))) << 8)
      | (fp8e(bf2f((unsigned short)(q.y & 0xFFFF))) << 16)
      | (fp8e(bf2f((unsigned short)(q.y >> 16))) << 24);
  o.y = fp8e(bf2f((unsigned short)(q.z & 0xFFFF)))
      | (fp8e(bf2f((unsigned short)(q.z >> 16))) << 8)
      | (fp8e(bf2f((unsigned short)(q.w & 0xFFFF))) << 16)
      | (fp8e(bf2f((unsigned short)(q.w >> 16))) << 24);
  *(uint2*)(z1q + i) = o;
}

// ---------------- 128-wide propagate, fp8 gather ----------------
// r18: edge-word prefetch (1-pair lookahead); accumulation order identical
// to r16 (same slot/pair pairing into acc/acc2).
__global__ __launch_bounds__(256) void k_prop128(
    const unsigned char* __restrict__ inq, void* __restrict__ outp,
    const int* __restrict__ row_off, const unsigned int* __restrict__ edges,
    const float* __restrict__ dinv, int out_fp8) {
  int v = blockIdx.x * 4 + (threadIdx.x >> 6);
  if (v >= NODES) return;
  int lane = threadIdx.x & 63;
  int rb = row_off[v], re = row_off[v + 1];
  float dv = dinv[v];
  float wsw = dv * dv;
  int slot = lane >> 4, fl = lane & 15;
  float acc[8], acc2[8];
  {
    uint2 q = *(const uint2*)(inq + (size_t)v * 128 + fl * 8);
    float sw = (slot == 0) ? wsw : 0.f;
    float v8[8];
    dec8(q, v8);
    #pragma unroll
    for (int k = 0; k < 8; ++k) { acc[k] = sw * v8[k]; acc2[k] = 0.f; }
  }
  int j = rb + slot;
  if (j + 4 < re) {
    unsigned e1 = edges[j], e2 = edges[j + 4];
    j += 8;
    for (; j + 4 < re; j += 8) {
      unsigned n1 = edges[j], n2 = edges[j + 4];   // prefetch next pair
      int s1; float w1; unpack_edge(e1, s1, w1);
      int s2; float w2; unpack_edge(e2, s2, w2);
      uint2 q1 = *(const uint2*)(inq + (size_t)s1 * 128 + fl * 8);
      uint2 q2 = *(const uint2*)(inq + (size_t)s2 * 128 + fl * 8);
      macc8q(q1, acc, w1);
      macc8q(q2, acc2, w2);
      e1 = n1; e2 = n2;
    }
    // final prefetched pair
    int s1; float w1; unpack_edge(e1, s1, w1);
    int s2; float w2; unpack_edge(e2, s2, w2);
    uint2 q1 = *(const uint2*)(inq + (size_t)s1 * 128 + fl * 8);
    uint2 q2 = *(const uint2*)(inq + (size_t)s2 * 128 + fl * 8);
    macc8q(q1, acc, w1);
    macc8q(q2, acc2, w2);
  }
  if (j < re) {
    int s; float w; unpack_edge(edges[j], s, w);
    uint2 q = *(const uint2*)(inq + (size_t)s * 128 + fl * 8);
    macc8q(q, acc, w);
  }
  #pragma unroll
  for (int k = 0; k < 8; ++k) acc[k] += acc2[k];
  #pragma unroll
  for (int k = 0; k < 8; ++k) {
    acc[k] += __shfl_xor(acc[k], 32);
    acc[k] += __shfl_xor(acc[k], 16);
  }
  if (slot == 0) {
    #pragma unroll
    for (int k = 0; k < 8; ++k) acc[k] = fin(acc[k]);
    if (out_fp8) {
      uint2 o;
      o.x = fp8e(acc[0]) | (fp8e(acc[1]) << 8) | (fp8e(acc[2]) << 16) | (fp8e(acc[3]) << 24);
      o.y = fp8e(acc[4]) | (fp8e(acc[5]) << 8) | (fp8e(acc[6]) << 16) | (fp8e(acc[7]) << 24);
      *(uint2*)((unsigned char*)outp + (size_t)v * 128 + fl * 8) = o;
    } else {
      uint4 o = pack8(acc);
      *(uint4*)((unsigned short*)outp + (size_t)v * 128 + fl * 8) = o;
    }
  }
}

// ---------------- fused conv1+conv2 (r16/r12 structure, verified) --------
// lW/lW2/lA LDS staging, 3 barriers/g, z1 bf16 2-byte stores. CLOSED.
__global__ __launch_bounds__(256) void k_gemm_fused(
    const void* __restrict__ x, const unsigned char* __restrict__ x1q,
    const unsigned short* __restrict__ x2, const unsigned short* __restrict__ wt1,
    const unsigned short* __restrict__ wt2,
    const unsigned short* __restrict__ b0, const unsigned short* __restrict__ b1,
    const unsigned short* __restrict__ b2, void* __restrict__ outp,
    unsigned short* __restrict__ z1, const int* __restrict__ flags) {
  __shared__ unsigned short lA[64 * 136];    // h tile only
  __shared__ unsigned short lW[128 * 136];   // W1_g [n][k]
  __shared__ unsigned short lW2[80 * 136];   // W2 slice [n][kk]
  int f32x = flags[0];
  int m0 = blockIdx.x * 64;
  int t = threadIdx.x;
  int wave = t >> 6, lane = t & 63;
  int lr = lane & 15, lq = lane >> 4;
  int wr = (wave >> 1) * 32, wc = (wave & 1) * 64;
  floatx4 zacc[5] = {};

  for (int g = 0; g < 3; ++g) {
    const unsigned short* Ab = (g == 0) ? (const unsigned short*)x : x2;
    const unsigned short* W = wt1 + g * 16384;
    const unsigned short* bias = (g == 0) ? b0 : (g == 1) ? b1 : b2;
    __syncthreads();   // prior z-phase lW2/lA reads complete
    for (int i = 0; i < 8; ++i) {            // W1: 128 x 16 chunks
      int idx = t + i * 256;
      int row = idx >> 4, c16 = idx & 15;
      *(uint4*)(&lW[row * 136 + c16 * 8]) =
          *(const uint4*)(W + row * 128 + c16 * 8);
    }
    for (int i = 0; i < 5; ++i) {            // W2 slice: 80 x 16
      int idx = t + i * 256;
      int n = idx >> 4, c16 = idx & 15;
      *(uint4*)(&lW2[n * 136 + c16 * 8]) =
          *(const uint4*)(wt2 + n * 384 + g * 128 + c16 * 8);
    }
    __syncthreads();

    // h-phase: A fragments straight from global
    floatx4 acc[2][4] = {};
    for (int ks = 0; ks < 4; ++ks) {
      int k0 = ks * 32 + lq * 8;
      bf16x8 af[2], bfr[4];
      for (int i = 0; i < 2; ++i) {
        int gr = m0 + wr + i * 16 + lr;
        if (gr < NODES) {
          if (g == 1) {
            uint2 qq = *(const uint2*)(x1q + (size_t)gr * 128 + k0);
            float tv[8];
            dec8(qq, tv);
            uint4 t4 = pack8(tv);
            af[i] = __builtin_bit_cast(bf16x8, t4);
          } else if (g == 0 && f32x) {
            uint4 t4 = pack8((const float*)x + (size_t)gr * 128 + k0);
            af[i] = __builtin_bit_cast(bf16x8, t4);
          } else {
            af[i] = *(const bf16x8*)(Ab + (size_t)gr * 128 + k0);
          }
        } else {
          uint4 zz = {0, 0, 0, 0};
          af[i] = __builtin_bit_cast(bf16x8, zz);
        }
      }
      for (int j = 0; j < 4; ++j)
        bfr[j] = *(const bf16x8*)(&lW[(wc + j * 16 + lr) * 136 + k0]);
      for (int i = 0; i < 2; ++i)
        for (int j = 0; j < 4; ++j)
          acc[i][j] = __builtin_amdgcn_mfma_f32_16x16x32_bf16(af[i], bfr[j], acc[i][j], 0, 0, 0);
    }
    // h -> LDS (lA free: last reads were before top-of-loop barrier)
    for (int i = 0; i < 2; ++i) {
      int rloc = wr + i * 16 + lq * 4;
      for (int j = 0; j < 4; ++j) {
        int col = wc + j * 16 + lr;
        float bv = bf2f(bias[col]);
        for (int r = 0; r < 4; ++r) {
          float val = acc[i][j][r] + bv;
          val = val > 0.f ? val : 0.f;       // relu (squashes NaN too)
          lA[(rloc + r) * 136 + col] = f2bf(val);
        }
      }
    }
    __syncthreads();
    // z-phase
    for (int ks = 0; ks < 4; ++ks) {
      int k0 = ks * 32 + lq * 8;
      bf16x8 ah = *(const bf16x8*)(&lA[(wave * 16 + lr) * 136 + k0]);
      bf16x8 bw[5];
      for (int j = 0; j < 5; ++j)
        bw[j] = *(const bf16x8*)(&lW2[(j * 16 + lr) * 136 + k0]);
      for (int j = 0; j < 5; ++j)
        zacc[j] = __builtin_amdgcn_mfma_f32_16x16x32_bf16(ah, bw[j], zacc[j], 0, 0, 0);
    }
  }
  int rbase = m0 + wave * 16 + lq * 4;
  for (int j = 0; j < 5; ++j) {
    int col = j * 16 + lr;
    for (int r = 0; r < 4; ++r) {
      int gr = rbase + r;
      if (gr < NODES) {
        float vv = zacc[j][r];
        if (col < 40) {
          if (f32x) ((float*)outp)[(size_t)gr * 80 + col] = vv;
          else ((unsigned short*)outp)[(size_t)gr * 80 + col] = f2bf(vv);
        } else {
          z1[(size_t)gr * 40 + (col - 40)] = f2bf(vv);
        }
      }
    }
  }
}

// ---------------- fused 40-d propagate + bias + log_softmax ----------------
// r13 fp8 z1 path + r18 edge-word prefetch (order identical to r16).
__global__ __launch_bounds__(256) void k_prop40_softmax(
    const unsigned char* __restrict__ z1q, const unsigned short* __restrict__ b2_0,
    const unsigned short* __restrict__ b2_1, const int* __restrict__ row_off,
    const unsigned int* __restrict__ edges, const float* __restrict__ dinv,
    void* __restrict__ outp, const int* __restrict__ flags) {
  int f32o = flags[0];
  int v = blockIdx.x * 4 + (threadIdx.x >> 6);
  if (v >= NODES) return;
  int lane = threadIdx.x & 63;
  int slot = lane >> 5, fl = lane & 31;
  bool gact = fl < 20;
  int fo = gact ? fl * 2 : 0;
  int rb = row_off[v], re = row_off[v + 1];
  float dv = dinv[v];
  float wsw = dv * dv;
  float ax = 0.f, ay = 0.f, bx = 0.f, by = 0.f;
  if (slot == 0) {
    unsigned int p = *(const unsigned short*)(z1q + (size_t)v * 40 + fo);
    floatx2 d = dec2(p);
    ax = wsw * d[0];
    ay = wsw * d[1];
  }
  int j = rb + slot;
  if (j + 2 < re) {
    unsigned e1 = edges[j], e2 = edges[j + 2];
    j += 4;
    for (; j + 2 < re; j += 4) {
      unsigned n1 = edges[j], n2 = edges[j + 2];   // prefetch next pair
      int s1; float w1; unpack_edge(e1, s1, w1);
      int s2; float w2; unpack_edge(e2, s2, w2);
      unsigned int q1 = *(const unsigned short*)(z1q + (size_t)s1 * 40 + fo);
      unsigned int q2 = *(const unsigned short*)(z1q + (size_t)s2 * 40 + fo);
      floatx2 d1 = dec2(q1);
      floatx2 d2 = dec2(q2);
      ax += w1 * d1[0];
      ay += w1 * d1[1];
      bx += w2 * d2[0];
      by += w2 * d2[1];
      e1 = n1; e2 = n2;
    }
    // final prefetched pair
    int s1; float w1; unpack_edge(e1, s1, w1);
    int s2; float w2; unpack_edge(e2, s2, w2);
    unsigned int q1 = *(const unsigned short*)(z1q + (size_t)s1 * 40 + fo);
    unsigned int q2 = *(const unsigned short*)(z1q + (size_t)s2 * 40 + fo);
    floatx2 d1 = dec2(q1);
    floatx2 d2 = dec2(q2);
    ax += w1 * d1[0];
    ay += w1 * d1[1];
    bx += w2 * d2[0];
    by += w2 * d2[1];
  }
  if (j < re) {
    int s; float w; unpack_edge(edges[j], s, w);
    unsigned int q = *(const unsigned short*)(z1q + (size_t)s * 40 + fo);
    floatx2 d = dec2(q);
    ax += w * d[0];
    ay += w * d[1];
  }
  ax += bx; ay += by;
  ax += __shfl_xor(ax, 32);
  ay += __shfl_xor(ay, 32);
  bool act = lane < 20;
  float l0x = 0.f, l0y = 0.f, l1x = 0.f, l1y = 0.f;
  if (act) {
    l0x = fin(ldf(outp, (size_t)v * 80 + fo, f32o)     + bf2f(b2_0[fo]));
    l0y = fin(ldf(outp, (size_t)v * 80 + fo + 1, f32o) + bf2f(b2_0[fo + 1]));
    l1x = fin(ax + bf2f(b2_1[fo]));
    l1y = fin(ay + bf2f(b2_1[fo + 1]));
  }
  float m = act ? fmaxf(fmaxf(l0x, l0y), fmaxf(l1x, l1y)) : -INFINITY;
  for (int off = 32; off; off >>= 1) m = fmaxf(m, __shfl_xor(m, off));
  float s = act ? (expf(l0x - m) + expf(l0y - m) + expf(l1x - m) + expf(l1y - m)) : 0.f;
  for (int off = 32; off; off >>= 1) s += __shfl_xor(s, off);
  float lse = m + logf(s);
  if (act) {
    if (f32o) {
      float* of = (float*)outp;
      of[(size_t)v * 80 + fo]          = l0x - lse;
      of[(size_t)v * 80 + fo + 1]      = l0y - lse;
      of[(size_t)v * 80 + 40 + fo]     = l1x - lse;
      of[(size_t)v * 80 + 40 + fo + 1] = l1y - lse;
    } else {
      unsigned short* ob = (unsigned short*)outp;
      unsigned int o0 = ((unsigned int)f2bf(l0y - lse) << 16) | f2bf(l0x - lse);
      unsigned int o1 = ((unsigned int)f2bf(l1y - lse) << 16) | f2bf(l1x - lse);
      *(unsigned int*)(ob + (size_t)v * 80 + fo) = o0;
      *(unsigned int*)(ob + (size_t)v * 80 + 40 + fo) = o1;
    }
  }
}

// sentinel: ws too small — encode its MB count into the output
__global__ void k_sentinel(unsigned short* o, int n, float val) {
  int i = blockIdx.x * blockDim.x + threadIdx.x;
  if (i < n) o[i] = f2bf(val);
}

// ---------------- host ----------------

static inline size_t al256(size_t x) { return (x + 255) & ~(size_t)255; }

extern "C" void kernel_launch(void* const* d_in, const int* in_sizes, int n_in,
                              void* d_out, int out_size, void* d_ws, size_t ws_size,
                              hipStream_t stream) {
  const void* x    = d_in[0];
  const int*  ei   = (const int*)d_in[1];
  const void* w1_0 = d_in[2];
  const unsigned short* b1_0 = (const unsigned short*)d_in[3];
  const void* w1_1 = d_in[4];
  const unsigned short* b1_1 = (const unsigned short*)d_in[5];
  const void* w1_2 = d_in[6];
  const unsigned short* b1_2 = (const unsigned short*)d_in[7];
  const void* w2_0 = d_in[8];
  const unsigned short* b2_0 = (const unsigned short*)d_in[9];
  const void* w2_1 = d_in[10];
  const unsigned short* b2_1 = (const unsigned short*)d_in[11];
  const int* srcv = ei;
  const int* dstv = ei + NEDGE;

  // ws layout: same 33.8 MB total as r4-r17. z1 slot holds bf16 z1 (4MB).
  // rank[] AND z1q both alias the x2v slot at disjoint times:
  // rank (count/fill, early) -> x2v (prop128-pass2..gemm) -> z1q (quant_z..prop40).
  char* p = (char*)d_ws;
  int*   flags   = (int*)p;               p += al256(2 * 4);
  int*   row_off = (int*)p;               p += al256((NODES + 1) * 4);
  float* dinv    = (float*)p;             p += al256(NODES * 4);
  unsigned int* edges = (unsigned int*)p; p += al256((size_t)NEDGE * 4);
  unsigned short* wt1 = (unsigned short*)p; p += al256(3 * 128 * 128 * 2);
  unsigned short* wt2 = (unsigned short*)p; p += al256(80 * 384 * 2);
  unsigned char* xq  = (unsigned char*)p; p += al256((size_t)NODES * 128);
  unsigned char* x1q = (unsigned char*)p; p += al256((size_t)NODES * 128);
  unsigned short* x2v = (unsigned short*)p; p += al256((size_t)NODES * 128 * 2);
  unsigned short* z1 = (unsigned short*)p; p += al256((size_t)NODES * 40 * 2);
  int*   cnt     = (int*)p;               p += al256(NODES * 4);
  int*   cursor  = (int*)p;               p += al256(NODES * 4);
  int*   sums    = (int*)p;               p += al256(NSB * 4);
  int*   boff    = (int*)p;               p += al256(NSB * 4);
  size_t need = (size_t)(p - (char*)d_ws);
  int* rank = (int*)x2v;                 // early alias of x2v slot
  unsigned char* z1q = (unsigned char*)x2v;  // late alias (x2v dead post-gemm)
  (void)cursor;

  if (ws_size < need) {
    float val = -1000.f - (float)(ws_size >> 20);
    k_sentinel<<<(out_size + 255) / 256, 256, 0, stream>>>(
        (unsigned short*)d_out, out_size, val);
    return;
  }

  hipMemsetAsync(cnt, 0, al256(NODES * 4) + NODES * 4, stream);
  k_count<<<NEDGE / 256, 256, 0, stream>>>(dstv, cnt, rank);
  k_scan_sum<<<NSB, 256, 0, stream>>>(cnt, sums, dinv,
                                      (const unsigned short*)x,
                                      (const unsigned short*)w1_0, flags);
  k_scan_top<<<1, 256, 0, stream>>>(sums, boff, row_off);
  k_scan_final<<<NSB, 256, 0, stream>>>(cnt, boff, row_off);
  k_quant_x<<<(NODES * 128 / 8) / 256, 256, 0, stream>>>(x, xq, flags);
  k_fill_prep<<<FILL_BLOCKS + 312, 256, 0, stream>>>(
      srcv, dstv, row_off, rank, dinv, edges,
      w1_0, w1_1, w1_2, w2_0, w2_1, flags, wt1, wt2);
  k_prop128<<<NODES / 4, 256, 0, stream>>>(xq, x1q, row_off, edges, dinv, 1);
  k_prop128<<<NODES / 4, 256, 0, stream>>>(x1q, x2v, row_off, edges, dinv, 0);
  k_gemm_fused<<<(NODES + 63) / 64, 256, 0, stream>>>(x, x1q, x2v, wt1, wt2,
                                                      b1_0, b1_1, b1_2, d_out, z1, flags);
  k_quant_z<<<(NODES * 40 / 8 + 255) / 256, 256, 0, stream>>>(z1, z1q);
  k_prop40_softmax<<<NODES / 4, 256, 0, stream>>>(z1q, b2_0, b2_1, row_off, edges,
                                                  dinv, d_out, flags);
}

// Round 13
// 280.892 us; speedup vs baseline: 1.1186x; 1.0142x over previous
//
#include <hip/hip_runtime.h>
#include <stdint.h>

// MixHopNet, MI355X (gfx950). r19 (=r18) verified 284.9us, absmax 0.03125
// (bitwise-identical accum confirmed). Edge prefetch: +4us (props near
// gather-latency floor). All kernels < 42us; kernel-sum ~180 vs wall 285
// -> ~100us of launch gaps over 12 dispatches (~8-10us each).
// r20: cut dispatch count. (1) gemm epilogue writes z1q fp8 DIRECTLY
// (r13's exact epilogue; r13 wall 289.2 == r16 wall 289.1 proves
// wall-neutral - the "58us" was profiling-replay artifact) -> drop
// k_quant_z. (2) k_quant_x folded into k_fill_prep grid (+3125 blocks;
// flags valid by then). 12 -> 10 dispatches.
// Predicted: wall 284.9 -> ~268-277, fill_prep +~3us, absmax 0.03125.
// If <5us -> gaps smaller than modeled; near family floor.

#define NODES 50000
#define NEDGE 800000
#define NSB   ((NODES + 255) / 256)   // 196

typedef __bf16 bf16x8 __attribute__((ext_vector_type(8)));
typedef float  floatx4 __attribute__((ext_vector_type(4)));
typedef float  floatx2 __attribute__((ext_vector_type(2)));

#if defined(__has_builtin)
#if __has_builtin(__builtin_amdgcn_cvt_pk_f32_fp8)
#define HW_FP8 1
#endif
#endif
#ifndef HW_FP8
#define HW_FP8 0
#endif

__device__ __forceinline__ float bf2f(unsigned short u) {
  unsigned int x = ((unsigned int)u) << 16;
  return __builtin_bit_cast(float, x);
}
__device__ __forceinline__ unsigned short f2bf(float f) {
  unsigned int x = __builtin_bit_cast(unsigned int, f);
  x += 0x7FFFu + ((x >> 16) & 1u);   // RNE
  return (unsigned short)(x >> 16);
}
__device__ __forceinline__ float ldf(const void* p, size_t i, int f32) {
  return f32 ? ((const float*)p)[i] : bf2f(((const unsigned short*)p)[i]);
}
__device__ __forceinline__ float fin(float x) { return __builtin_isfinite(x) ? x : 0.f; }
__device__ __forceinline__ uint4 pack8(const float* f) {
  float4 a = ((const float4*)f)[0], b = ((const float4*)f)[1];
  uint4 r;
  r.x = (unsigned)f2bf(a.x) | ((unsigned)f2bf(a.y) << 16);
  r.y = (unsigned)f2bf(a.z) | ((unsigned)f2bf(a.w) << 16);
  r.z = (unsigned)f2bf(b.x) | ((unsigned)f2bf(b.y) << 16);
  r.w = (unsigned)f2bf(b.z) | ((unsigned)f2bf(b.w) << 16);
  return r;
}

// ---- fp8 e4m3fn codec ----
__device__ __forceinline__ float fp8d(unsigned int b) {
  unsigned int bits = ((b & 0x80u) << 24) | ((b & 0x7Fu) << 20);
  return __builtin_bit_cast(float, bits) * __builtin_bit_cast(float, 0x7B800000u);
}
__device__ __forceinline__ floatx2 dec2(unsigned int u) {
#if HW_FP8
  return __builtin_amdgcn_cvt_pk_f32_fp8((int)u, false);
#else
  floatx2 r; r[0] = fp8d(u); r[1] = fp8d(u >> 8); return r;
#endif
}
__device__ __forceinline__ void dec8(uint2 q, float* v) {
#if HW_FP8
  floatx2 a = __builtin_amdgcn_cvt_pk_f32_fp8((int)q.x, false);
  floatx2 b = __builtin_amdgcn_cvt_pk_f32_fp8((int)q.x, true);
  floatx2 c = __builtin_amdgcn_cvt_pk_f32_fp8((int)q.y, false);
  floatx2 d = __builtin_amdgcn_cvt_pk_f32_fp8((int)q.y, true);
  v[0] = a[0]; v[1] = a[1]; v[2] = b[0]; v[3] = b[1];
  v[4] = c[0]; v[5] = c[1]; v[6] = d[0]; v[7] = d[1];
#else
  v[0] = fp8d(q.x);       v[1] = fp8d(q.x >> 8);
  v[2] = fp8d(q.x >> 16); v[3] = fp8d(q.x >> 24);
  v[4] = fp8d(q.y);       v[5] = fp8d(q.y >> 8);
  v[6] = fp8d(q.y >> 16); v[7] = fp8d(q.y >> 24);
#endif
}
// encode: clamp to +-448, f32->f16 RNE (hw), round mantissa 10->3 RNE with
// natural carry, rebias 15->7. |v| < 2^-6 flushes to signed zero.
__device__ __forceinline__ unsigned int fp8e(float f) {
  f = fminf(fmaxf(f, -448.f), 448.f);
  unsigned int u = (unsigned int)__builtin_bit_cast(unsigned short, (_Float16)f);
  unsigned int r = u + 0x3Fu + ((u >> 7) & 1u);
  unsigned int e5 = (r >> 10) & 0x1Fu;
  unsigned int sgn = (u >> 8) & 0x80u;
  unsigned int out = ((r >> 7) & 7u) | ((e5 - 8u) << 3) | sgn;
  return (e5 < 9u) ? sgn : out;
}
__device__ __forceinline__ void macc8q(uint2 q, float* a, float w) {
  float v[8];
  dec8(q, v);
  #pragma unroll
  for (int k = 0; k < 8; ++k) a[k] += w * v[k];
}

// ---------------- graph preprocessing ----------------

__global__ void k_count(const int* __restrict__ dst, int* __restrict__ cnt,
                        int* __restrict__ rank) {
  int e = blockIdx.x * blockDim.x + threadIdx.x;
  if (e < NEDGE) rank[e] = atomicAdd(&cnt[dst[e]], 1);
}

__global__ void k_scan_sum(const int* __restrict__ cnt, int* __restrict__ sums,
                           float* __restrict__ dinv,
                           const unsigned short* __restrict__ xs,
                           const unsigned short* __restrict__ ws_,
                           int* __restrict__ flags) {
  __shared__ int sdata[256];
  int t = threadIdx.x, idx = blockIdx.x * 256 + t;
  int c = (idx < NODES) ? cnt[idx] : 0;
  if (idx < NODES) dinv[idx] = rsqrtf((float)c + 1.0f);   // +1 self loop
  sdata[t] = c;
  __syncthreads();
  for (int off = 128; off; off >>= 1) {
    if (t < off) sdata[t] += sdata[t + off];
    __syncthreads();
  }
  if (t == 0) sums[blockIdx.x] = sdata[0];
  if (blockIdx.x == 0 && t < 64) {
    const unsigned short* ptrs[2] = {xs, ws_};
    for (int k = 0; k < 2; ++k) {
      int bad = 0;
      for (int i = 0; i < 4; ++i) {
        float v = bf2f(ptrs[k][t * 4 + i]);
        float a = fabsf(v);
        if (!(a <= 1e4f) || (v != 0.f && a < 1e-10f)) bad++;   // NaN fails a<=1e4
      }
      for (int off = 32; off; off >>= 1) bad += __shfl_xor(bad, off);
      if (t == 0) flags[k] = (bad > 16) ? 1 : 0;   // 1 = fp32
    }
  }
}

__global__ void k_scan_top(const int* __restrict__ sums, int* __restrict__ boff,
                           int* __restrict__ row_off) {
  __shared__ int sdata[256];
  int t = threadIdx.x;
  int v = (t < NSB) ? sums[t] : 0;
  int cur = v;
  sdata[t] = cur; __syncthreads();
  for (int off = 1; off < 256; off <<= 1) {
    int add = (t >= off) ? sdata[t - off] : 0;
    __syncthreads();
    cur += add; sdata[t] = cur;
    __syncthreads();
  }
  if (t < NSB) boff[t] = cur - v;           // exclusive
  if (t == NSB - 1) row_off[NODES] = cur;   // total == NEDGE
}

__global__ void k_scan_final(const int* __restrict__ cnt, const int* __restrict__ boff,
                             int* __restrict__ row_off) {
  __shared__ int sdata[256];
  int t = threadIdx.x, idx = blockIdx.x * 256 + t;
  int v = (idx < NODES) ? cnt[idx] : 0;
  int cur = v;
  sdata[t] = cur; __syncthreads();
  for (int off = 1; off < 256; off <<= 1) {
    int add = (t >= off) ? sdata[t - off] : 0;
    __syncthreads();
    cur += add; sdata[t] = cur;
    __syncthreads();
  }
  if (idx < NODES) row_off[idx] = boff[blockIdx.x] + cur - v;
}

#define FILL_BLOCKS (NEDGE / 256)   // 3125
#define QX_BLOCKS   (NODES * 128 / 8 / 256)   // 3125

// r12: no atomics; pos = row_off[d] + rank[e].
// r20: quant_x folded in as trailing blocks (flags valid by launch time).
__global__ void k_fill_prep(const int* __restrict__ src, const int* __restrict__ dst,
                            const int* __restrict__ row_off, const int* __restrict__ rank,
                            const float* __restrict__ dinv, unsigned int* __restrict__ edges,
                            const void* __restrict__ w1_0, const void* __restrict__ w1_1,
                            const void* __restrict__ w1_2, const void* __restrict__ w2_0,
                            const void* __restrict__ w2_1, const int* __restrict__ flags,
                            unsigned short* __restrict__ wt1, unsigned short* __restrict__ wt2,
                            const void* __restrict__ x, unsigned char* __restrict__ xq) {
  if (blockIdx.x < FILL_BLOCKS) {
    int e = blockIdx.x * 256 + threadIdx.x;
    int s = src[e], d = dst[e];
    int pos = row_off[d] + rank[e];
    float w = dinv[s] * dinv[d];
    _Float16 hw = (_Float16)w;
    edges[pos] = ((unsigned int)__builtin_bit_cast(unsigned short, hw) << 16)
               | (unsigned int)(s & 0xFFFF);
  } else if (blockIdx.x < FILL_BLOCKS + 312) {
    int fw = flags[1];
    int idx = (blockIdx.x - FILL_BLOCKS) * 256 + threadIdx.x;
    if (idx < 3 * 128 * 128) {
      int g = idx / 16384, r = idx % 16384;
      int n = r / 128, k = r % 128;
      const void* w = (g == 0) ? w1_0 : (g == 1) ? w1_1 : w1_2;
      wt1[idx] = f2bf(ldf(w, (size_t)k * 128 + n, fw));
    } else {
      int r = idx - 49152;   // 312*256 - 49152 = 30720 = 80*384 exactly
      int n = r / 384, k = r % 384;
      float v = (n < 40) ? ldf(w2_0, (size_t)k * 40 + n, fw)
                         : ldf(w2_1, (size_t)k * 40 + (n - 40), fw);
      wt2[r] = f2bf(v);
    }
  } else {
    // quant_x work (r10 kernel, folded)
    int f32 = flags[0];
    size_t i = ((size_t)(blockIdx.x - FILL_BLOCKS - 312) * 256 + threadIdx.x) * 8;
    float v[8];
    if (f32) {
      const float* xf = (const float*)x;
      #pragma unroll
      for (int k = 0; k < 8; ++k) v[k] = xf[i + k];
    } else {
      uint4 q = *(const uint4*)((const unsigned short*)x + i);
      v[0] = bf2f((unsigned short)(q.x & 0xFFFF));
      v[1] = bf2f((unsigned short)(q.x >> 16));
      v[2] = bf2f((unsigned short)(q.y & 0xFFFF));
      v[3] = bf2f((unsigned short)(q.y >> 16));
      v[4] = bf2f((unsigned short)(q.z & 0xFFFF));
      v[5] = bf2f((unsigned short)(q.z >> 16));
      v[6] = bf2f((unsigned short)(q.w & 0xFFFF));
      v[7] = bf2f((unsigned short)(q.w >> 16));
    }
    uint2 o;
    o.x = fp8e(v[0]) | (fp8e(v[1]) << 8) | (fp8e(v[2]) << 16) | (fp8e(v[3]) << 24);
    o.y = fp8e(v[4]) | (fp8e(v[5]) << 8) | (fp8e(v[6]) << 16) | (fp8e(v[7]) << 24);
    *(uint2*)(xq + i) = o;
  }
}

__device__ __forceinline__ void unpack_edge(unsigned int e, int& s, float& w) {
  s = (int)(e & 0xFFFFu);
  w = (float)__builtin_bit_cast(_Float16, (unsigned short)(e >> 16));
}

// ---------------- 128-wide propagate, fp8 gather ----------------
// r18: edge-word prefetch (1-pair lookahead); accumulation order identical
// to r16 (same slot/pair pairing into acc/acc2).
__global__ __launch_bounds__(256) void k_prop128(
    const unsigned char* __restrict__ inq, void* __restrict__ outp,
    const int* __restrict__ row_off, const unsigned int* __restrict__ edges,
    const float* __restrict__ dinv, int out_fp8) {
  int v = blockIdx.x * 4 + (threadIdx.x >> 6);
  if (v >= NODES) return;
  int lane = threadIdx.x & 63;
  int rb = row_off[v], re = row_off[v + 1];
  float dv = dinv[v];
  float wsw = dv * dv;
  int slot = lane >> 4, fl = lane & 15;
  float acc[8], acc2[8];
  {
    uint2 q = *(const uint2*)(inq + (size_t)v * 128 + fl * 8);
    float sw = (slot == 0) ? wsw : 0.f;
    float v8[8];
    dec8(q, v8);
    #pragma unroll
    for (int k = 0; k < 8; ++k) { acc[k] = sw * v8[k]; acc2[k] = 0.f; }
  }
  int j = rb + slot;
  if (j + 4 < re) {
    unsigned e1 = edges[j], e2 = edges[j + 4];
    j += 8;
    for (; j + 4 < re; j += 8) {
      unsigned n1 = edges[j], n2 = edges[j + 4];   // prefetch next pair
      int s1; float w1; unpack_edge(e1, s1, w1);
      int s2; float w2; unpack_edge(e2, s2, w2);
      uint2 q1 = *(const uint2*)(inq + (size_t)s1 * 128 + fl * 8);
      uint2 q2 = *(const uint2*)(inq + (size_t)s2 * 128 + fl * 8);
      macc8q(q1, acc, w1);
      macc8q(q2, acc2, w2);
      e1 = n1; e2 = n2;
    }
    // final prefetched pair
    int s1; float w1; unpack_edge(e1, s1, w1);
    int s2; float w2; unpack_edge(e2, s2, w2);
    uint2 q1 = *(const uint2*)(inq + (size_t)s1 * 128 + fl * 8);
    uint2 q2 = *(const uint2*)(inq + (size_t)s2 * 128 + fl * 8);
    macc8q(q1, acc, w1);
    macc8q(q2, acc2, w2);
  }
  if (j < re) {
    int s; float w; unpack_edge(edges[j], s, w);
    uint2 q = *(const uint2*)(inq + (size_t)s * 128 + fl * 8);
    macc8q(q, acc, w);
  }
  #pragma unroll
  for (int k = 0; k < 8; ++k) acc[k] += acc2[k];
  #pragma unroll
  for (int k = 0; k < 8; ++k) {
    acc[k] += __shfl_xor(acc[k], 32);
    acc[k] += __shfl_xor(acc[k], 16);
  }
  if (slot == 0) {
    #pragma unroll
    for (int k = 0; k < 8; ++k) acc[k] = fin(acc[k]);
    if (out_fp8) {
      uint2 o;
      o.x = fp8e(acc[0]) | (fp8e(acc[1]) << 8) | (fp8e(acc[2]) << 16) | (fp8e(acc[3]) << 24);
      o.y = fp8e(acc[4]) | (fp8e(acc[5]) << 8) | (fp8e(acc[6]) << 16) | (fp8e(acc[7]) << 24);
      *(uint2*)((unsigned char*)outp + (size_t)v * 128 + fl * 8) = o;
    } else {
      uint4 o = pack8(acc);
      *(uint4*)((unsigned short*)outp + (size_t)v * 128 + fl * 8) = o;
    }
  }
}

// ---------------- fused conv1+conv2 (r16/r12 structure; r13 epilogue) ----
// lW/lW2/lA LDS staging, 3 barriers/g. r20: z1 written as fp8 directly
// (r13's epilogue, proven wall-neutral) -> no quant_z kernel.
__global__ __launch_bounds__(256) void k_gemm_fused(
    const void* __restrict__ x, const unsigned char* __restrict__ x1q,
    const unsigned short* __restrict__ x2, const unsigned short* __restrict__ wt1,
    const unsigned short* __restrict__ wt2,
    const unsigned short* __restrict__ b0, const unsigned short* __restrict__ b1,
    const unsigned short* __restrict__ b2, void* __restrict__ outp,
    unsigned char* __restrict__ z1q, const int* __restrict__ flags) {
  __shared__ unsigned short lA[64 * 136];    // h tile only
  __shared__ unsigned short lW[128 * 136];   // W1_g [n][k]
  __shared__ unsigned short lW2[80 * 136];   // W2 slice [n][kk]
  int f32x = flags[0];
  int m0 = blockIdx.x * 64;
  int t = threadIdx.x;
  int wave = t >> 6, lane = t & 63;
  int lr = lane & 15, lq = lane >> 4;
  int wr = (wave >> 1) * 32, wc = (wave & 1) * 64;
  floatx4 zacc[5] = {};

  for (int g = 0; g < 3; ++g) {
    const unsigned short* Ab = (g == 0) ? (const unsigned short*)x : x2;
    const unsigned short* W = wt1 + g * 16384;
    const unsigned short* bias = (g == 0) ? b0 : (g == 1) ? b1 : b2;
    __syncthreads();   // prior z-phase lW2/lA reads complete
    for (int i = 0; i < 8; ++i) {            // W1: 128 x 16 chunks
      int idx = t + i * 256;
      int row = idx >> 4, c16 = idx & 15;
      *(uint4*)(&lW[row * 136 + c16 * 8]) =
          *(const uint4*)(W + row * 128 + c16 * 8);
    }
    for (int i = 0; i < 5; ++i) {            // W2 slice: 80 x 16
      int idx = t + i * 256;
      int n = idx >> 4, c16 = idx & 15;
      *(uint4*)(&lW2[n * 136 + c16 * 8]) =
          *(const uint4*)(wt2 + n * 384 + g * 128 + c16 * 8);
    }
    __syncthreads();

    // h-phase: A fragments straight from global
    floatx4 acc[2][4] = {};
    for (int ks = 0; ks < 4; ++ks) {
      int k0 = ks * 32 + lq * 8;
      bf16x8 af[2], bfr[4];
      for (int i = 0; i < 2; ++i) {
        int gr = m0 + wr + i * 16 + lr;
        if (gr < NODES) {
          if (g == 1) {
            uint2 qq = *(const uint2*)(x1q + (size_t)gr * 128 + k0);
            float tv[8];
            dec8(qq, tv);
            uint4 t4 = pack8(tv);
            af[i] = __builtin_bit_cast(bf16x8, t4);
          } else if (g == 0 && f32x) {
            uint4 t4 = pack8((const float*)x + (size_t)gr * 128 + k0);
            af[i] = __builtin_bit_cast(bf16x8, t4);
          } else {
            af[i] = *(const bf16x8*)(Ab + (size_t)gr * 128 + k0);
          }
        } else {
          uint4 zz = {0, 0, 0, 0};
          af[i] = __builtin_bit_cast(bf16x8, zz);
        }
      }
      for (int j = 0; j < 4; ++j)
        bfr[j] = *(const bf16x8*)(&lW[(wc + j * 16 + lr) * 136 + k0]);
      for (int i = 0; i < 2; ++i)
        for (int j = 0; j < 4; ++j)
          acc[i][j] = __builtin_amdgcn_mfma_f32_16x16x32_bf16(af[i], bfr[j], acc[i][j], 0, 0, 0);
    }
    // h -> LDS (lA free: last reads were before top-of-loop barrier)
    for (int i = 0; i < 2; ++i) {
      int rloc = wr + i * 16 + lq * 4;
      for (int j = 0; j < 4; ++j) {
        int col = wc + j * 16 + lr;
        float bv = bf2f(bias[col]);
        for (int r = 0; r < 4; ++r) {
          float val = acc[i][j][r] + bv;
          val = val > 0.f ? val : 0.f;       // relu (squashes NaN too)
          lA[(rloc + r) * 136 + col] = f2bf(val);
        }
      }
    }
    __syncthreads();
    // z-phase
    for (int ks = 0; ks < 4; ++ks) {
      int k0 = ks * 32 + lq * 8;
      bf16x8 ah = *(const bf16x8*)(&lA[(wave * 16 + lr) * 136 + k0]);
      bf16x8 bw[5];
      for (int j = 0; j < 5; ++j)
        bw[j] = *(const bf16x8*)(&lW2[(j * 16 + lr) * 136 + k0]);
      for (int j = 0; j < 5; ++j)
        zacc[j] = __builtin_amdgcn_mfma_f32_16x16x32_bf16(ah, bw[j], zacc[j], 0, 0, 0);
    }
  }
  int rbase = m0 + wave * 16 + lq * 4;
  for (int j = 0; j < 5; ++j) {
    int col = j * 16 + lr;
    for (int r = 0; r < 4; ++r) {
      int gr = rbase + r;
      if (gr < NODES) {
        float vv = zacc[j][r];
        if (col < 40) {
          if (f32x) ((float*)outp)[(size_t)gr * 80 + col] = vv;
          else ((unsigned short*)outp)[(size_t)gr * 80 + col] = f2bf(vv);
        } else {
          z1q[(size_t)gr * 40 + (col - 40)] = (unsigned char)fp8e(vv);
        }
      }
    }
  }
}

// ---------------- fused 40-d propagate + bias + log_softmax ----------------
// r13 fp8 z1 path + r18 edge-word prefetch (order identical to r16).
__global__ __launch_bounds__(256) void k_prop40_softmax(
    const unsigned char* __restrict__ z1q, const unsigned short* __restrict__ b2_0,
    const unsigned short* __restrict__ b2_1, const int* __restrict__ row_off,
    const unsigned int* __restrict__ edges, const float* __restrict__ dinv,
    void* __restrict__ outp, const int* __restrict__ flags) {
  int f32o = flags[0];
  int v = blockIdx.x * 4 + (threadIdx.x >> 6);
  if (v >= NODES) return;
  int lane = threadIdx.x & 63;
  int slot = lane >> 5, fl = lane & 31;
  bool gact = fl < 20;
  int fo = gact ? fl * 2 : 0;
  int rb = row_off[v], re = row_off[v + 1];
  float dv = dinv[v];
  float wsw = dv * dv;
  float ax = 0.f, ay = 0.f, bx = 0.f, by = 0.f;
  if (slot == 0) {
    unsigned int p = *(const unsigned short*)(z1q + (size_t)v * 40 + fo);
    floatx2 d = dec2(p);
    ax = wsw * d[0];
    ay = wsw * d[1];
  }
  int j = rb + slot;
  if (j + 2 < re) {
    unsigned e1 = edges[j], e2 = edges[j + 2];
    j += 4;
    for (; j + 2 < re; j += 4) {
      unsigned n1 = edges[j], n2 = edges[j + 2];   // prefetch next pair
      int s1; float w1; unpack_edge(e1, s1, w1);
      int s2; float w2; unpack_edge(e2, s2, w2);
      unsigned int q1 = *(const unsigned short*)(z1q + (size_t)s1 * 40 + fo);
      unsigned int q2 = *(const unsigned short*)(z1q + (size_t)s2 * 40 + fo);
      floatx2 d1 = dec2(q1);
      floatx2 d2 = dec2(q2);
      ax += w1 * d1[0];
      ay += w1 * d1[1];
      bx += w2 * d2[0];
      by += w2 * d2[1];
      e1 = n1; e2 = n2;
    }
    // final prefetched pair
    int s1; float w1; unpack_edge(e1, s1, w1);
    int s2; float w2; unpack_edge(e2, s2, w2);
    unsigned int q1 = *(const unsigned short*)(z1q + (size_t)s1 * 40 + fo);
    unsigned int q2 = *(const unsigned short*)(z1q + (size_t)s2 * 40 + fo);
    floatx2 d1 = dec2(q1);
    floatx2 d2 = dec2(q2);
    ax += w1 * d1[0];
    ay += w1 * d1[1];
    bx += w2 * d2[0];
    by += w2 * d2[1];
  }
  if (j < re) {
    int s; float w; unpack_edge(edges[j], s, w);
    unsigned int q = *(const unsigned short*)(z1q + (size_t)s * 40 + fo);
    floatx2 d = dec2(q);
    ax += w * d[0];
    ay += w * d[1];
  }
  ax += bx; ay += by;
  ax += __shfl_xor(ax, 32);
  ay += __shfl_xor(ay, 32);
  bool act = lane < 20;
  float l0x = 0.f, l0y = 0.f, l1x = 0.f, l1y = 0.f;
  if (act) {
    l0x = fin(ldf(outp, (size_t)v * 80 + fo, f32o)     + bf2f(b2_0[fo]));
    l0y = fin(ldf(outp, (size_t)v * 80 + fo + 1, f32o) + bf2f(b2_0[fo + 1]));
    l1x = fin(ax + bf2f(b2_1[fo]));
    l1y = fin(ay + bf2f(b2_1[fo + 1]));
  }
  float m = act ? fmaxf(fmaxf(l0x, l0y), fmaxf(l1x, l1y)) : -INFINITY;
  for (int off = 32; off; off >>= 1) m = fmaxf(m, __shfl_xor(m, off));
  float s = act ? (expf(l0x - m) + expf(l0y - m) + expf(l1x - m) + expf(l1y - m)) : 0.f;
  for (int off = 32; off; off >>= 1) s += __shfl_xor(s, off);
  float lse = m + logf(s);
  if (act) {
    if (f32o) {
      float* of = (float*)outp;
      of[(size_t)v * 80 + fo]          = l0x - lse;
      of[(size_t)v * 80 + fo + 1]      = l0y - lse;
      of[(size_t)v * 80 + 40 + fo]     = l1x - lse;
      of[(size_t)v * 80 + 40 + fo + 1] = l1y - lse;
    } else {
      unsigned short* ob = (unsigned short*)outp;
      unsigned int o0 = ((unsigned int)f2bf(l0y - lse) << 16) | f2bf(l0x - lse);
      unsigned int o1 = ((unsigned int)f2bf(l1y - lse) << 16) | f2bf(l1x - lse);
      *(unsigned int*)(ob + (size_t)v * 80 + fo) = o0;
      *(unsigned int*)(ob + (size_t)v * 80 + 40 + fo) = o1;
    }
  }
}

// sentinel: ws too small — encode its MB count into the output
__global__ void k_sentinel(unsigned short* o, int n, float val) {
  int i = blockIdx.x * blockDim.x + threadIdx.x;
  if (i < n) o[i] = f2bf(val);
}

// ---------------- host ----------------

static inline size_t al256(size_t x) { return (x + 255) & ~(size_t)255; }

extern "C" void kernel_launch(void* const* d_in, const int* in_sizes, int n_in,
                              void* d_out, int out_size, void* d_ws, size_t ws_size,
                              hipStream_t stream) {
  const void* x    = d_in[0];
  const int*  ei   = (const int*)d_in[1];
  const void* w1_0 = d_in[2];
  const unsigned short* b1_0 = (const unsigned short*)d_in[3];
  const void* w1_1 = d_in[4];
  const unsigned short* b1_1 = (const unsigned short*)d_in[5];
  const void* w1_2 = d_in[6];
  const unsigned short* b1_2 = (const unsigned short*)d_in[7];
  const void* w2_0 = d_in[8];
  const unsigned short* b2_0 = (const unsigned short*)d_in[9];
  const void* w2_1 = d_in[10];
  const unsigned short* b2_1 = (const unsigned short*)d_in[11];
  const int* srcv = ei;
  const int* dstv = ei + NEDGE;

  // ws layout: same 33.8 MB total as r4-r19. z1 bf16 slot now unused
  // (kept for layout stability). rank[] AND z1q alias the x2v slot at
  // disjoint times: rank (count..fill) -> x2v (prop128-pass2..gemm A-read)
  // -> z1q (gemm epilogue..prop40).
  char* p = (char*)d_ws;
  int*   flags   = (int*)p;               p += al256(2 * 4);
  int*   row_off = (int*)p;               p += al256((NODES + 1) * 4);
  float* dinv    = (float*)p;             p += al256(NODES * 4);
  unsigned int* edges = (unsigned int*)p; p += al256((size_t)NEDGE * 4);
  unsigned short* wt1 = (unsigned short*)p; p += al256(3 * 128 * 128 * 2);
  unsigned short* wt2 = (unsigned short*)p; p += al256(80 * 384 * 2);
  unsigned char* xq  = (unsigned char*)p; p += al256((size_t)NODES * 128);
  unsigned char* x1q = (unsigned char*)p; p += al256((size_t)NODES * 128);
  unsigned short* x2v = (unsigned short*)p; p += al256((size_t)NODES * 128 * 2);
  unsigned short* z1 = (unsigned short*)p; p += al256((size_t)NODES * 40 * 2);
  int*   cnt     = (int*)p;               p += al256(NODES * 4);
  int*   cursor  = (int*)p;               p += al256(NODES * 4);
  int*   sums    = (int*)p;               p += al256(NSB * 4);
  int*   boff    = (int*)p;               p += al256(NSB * 4);
  size_t need = (size_t)(p - (char*)d_ws);
  int* rank = (int*)x2v;                 // early alias of x2v slot
  unsigned char* z1q = (unsigned char*)x2v;  // late alias (x2v dead post-gemm A-read)
  (void)cursor; (void)z1;

  if (ws_size < need) {
    float val = -1000.f - (float)(ws_size >> 20);
    k_sentinel<<<(out_size + 255) / 256, 256, 0, stream>>>(
        (unsigned short*)d_out, out_size, val);
    return;
  }

  hipMemsetAsync(cnt, 0, al256(NODES * 4) + NODES * 4, stream);
  k_count<<<NEDGE / 256, 256, 0, stream>>>(dstv, cnt, rank);
  k_scan_sum<<<NSB, 256, 0, stream>>>(cnt, sums, dinv,
                                      (const unsigned short*)x,
                                      (const unsigned short*)w1_0, flags);
  k_scan_top<<<1, 256, 0, stream>>>(sums, boff, row_off);
  k_scan_final<<<NSB, 256, 0, stream>>>(cnt, boff, row_off);
  k_fill_prep<<<FILL_BLOCKS + 312 + QX_BLOCKS, 256, 0, stream>>>(
      srcv, dstv, row_off, rank, dinv, edges,
      w1_0, w1_1, w1_2, w2_0, w2_1, flags, wt1, wt2, x, xq);
  k_prop128<<<NODES / 4, 256, 0, stream>>>(xq, x1q, row_off, edges, dinv, 1);
  k_prop128<<<NODES / 4, 256, 0, stream>>>(x1q, x2v, row_off, edges, dinv, 0);
  k_gemm_fused<<<(NODES + 63) / 64, 256, 0, stream>>>(x, x1q, x2v, wt1, wt2,
                                                      b1_0, b1_1, b1_2, d_out, z1q, flags);
  k_prop40_softmax<<<NODES / 4, 256, 0, stream>>>(z1q, b2_0, b2_1, row_off, edges,
                                                  dinv, d_out, flags);
}

// Round 14
// 278.642 us; speedup vs baseline: 1.1277x; 1.0081x over previous
//
#include <hip/hip_runtime.h>
#include <stdint.h>

// MixHopNet, MI355X (gfx950). r20 verified 280.9us, absmax 0.03125.
// Fusions (drop quant_z via r13 epilogue; quant_x into fill_prep) = -4us
// -> per-dispatch gap ~2us (graph-captured), not 8-10. Fusion ceiling
// ~10-15us total across remaining 10 dispatches.
// r21: fold k_scan_top (SINGLE-BLOCK kernel: 1 block scans 196 sums while
// 255 CUs idle; ~4-6us wall) into k_scan_final - each of 196 blocks
// redundantly scans sums[] in LDS (L2-hot, trivial) and takes its own
// exclusive prefix. row_off[NODES] hardcoded = NEDGE (structural: every
// edge counted once). 10 -> 9 dispatches.
// Predicted: wall ~275-277, absmax 0.03125 exact (identical arithmetic).
// If <2us gain -> dispatch overhead mined out + all kernels resist their
// levers -> practical floor; declare next round.

#define NODES 50000
#define NEDGE 800000
#define NSB   ((NODES + 255) / 256)   // 196

typedef __bf16 bf16x8 __attribute__((ext_vector_type(8)));
typedef float  floatx4 __attribute__((ext_vector_type(4)));
typedef float  floatx2 __attribute__((ext_vector_type(2)));

#if defined(__has_builtin)
#if __has_builtin(__builtin_amdgcn_cvt_pk_f32_fp8)
#define HW_FP8 1
#endif
#endif
#ifndef HW_FP8
#define HW_FP8 0
#endif

__device__ __forceinline__ float bf2f(unsigned short u) {
  unsigned int x = ((unsigned int)u) << 16;
  return __builtin_bit_cast(float, x);
}
__device__ __forceinline__ unsigned short f2bf(float f) {
  unsigned int x = __builtin_bit_cast(unsigned int, f);
  x += 0x7FFFu + ((x >> 16) & 1u);   // RNE
  return (unsigned short)(x >> 16);
}
__device__ __forceinline__ float ldf(const void* p, size_t i, int f32) {
  return f32 ? ((const float*)p)[i] : bf2f(((const unsigned short*)p)[i]);
}
__device__ __forceinline__ float fin(float x) { return __builtin_isfinite(x) ? x : 0.f; }
__device__ __forceinline__ uint4 pack8(const float* f) {
  float4 a = ((const float4*)f)[0], b = ((const float4*)f)[1];
  uint4 r;
  r.x = (unsigned)f2bf(a.x) | ((unsigned)f2bf(a.y) << 16);
  r.y = (unsigned)f2bf(a.z) | ((unsigned)f2bf(a.w) << 16);
  r.z = (unsigned)f2bf(b.x) | ((unsigned)f2bf(b.y) << 16);
  r.w = (unsigned)f2bf(b.z) | ((unsigned)f2bf(b.w) << 16);
  return r;
}

// ---- fp8 e4m3fn codec ----
__device__ __forceinline__ float fp8d(unsigned int b) {
  unsigned int bits = ((b & 0x80u) << 24) | ((b & 0x7Fu) << 20);
  return __builtin_bit_cast(float, bits) * __builtin_bit_cast(float, 0x7B800000u);
}
__device__ __forceinline__ floatx2 dec2(unsigned int u) {
#if HW_FP8
  return __builtin_amdgcn_cvt_pk_f32_fp8((int)u, false);
#else
  floatx2 r; r[0] = fp8d(u); r[1] = fp8d(u >> 8); return r;
#endif
}
__device__ __forceinline__ void dec8(uint2 q, float* v) {
#if HW_FP8
  floatx2 a = __builtin_amdgcn_cvt_pk_f32_fp8((int)q.x, false);
  floatx2 b = __builtin_amdgcn_cvt_pk_f32_fp8((int)q.x, true);
  floatx2 c = __builtin_amdgcn_cvt_pk_f32_fp8((int)q.y, false);
  floatx2 d = __builtin_amdgcn_cvt_pk_f32_fp8((int)q.y, true);
  v[0] = a[0]; v[1] = a[1]; v[2] = b[0]; v[3] = b[1];
  v[4] = c[0]; v[5] = c[1]; v[6] = d[0]; v[7] = d[1];
#else
  v[0] = fp8d(q.x);       v[1] = fp8d(q.x >> 8);
  v[2] = fp8d(q.x >> 16); v[3] = fp8d(q.x >> 24);
  v[4] = fp8d(q.y);       v[5] = fp8d(q.y >> 8);
  v[6] = fp8d(q.y >> 16); v[7] = fp8d(q.y >> 24);
#endif
}
// encode: clamp to +-448, f32->f16 RNE (hw), round mantissa 10->3 RNE with
// natural carry, rebias 15->7. |v| < 2^-6 flushes to signed zero.
__device__ __forceinline__ unsigned int fp8e(float f) {
  f = fminf(fmaxf(f, -448.f), 448.f);
  unsigned int u = (unsigned int)__builtin_bit_cast(unsigned short, (_Float16)f);
  unsigned int r = u + 0x3Fu + ((u >> 7) & 1u);
  unsigned int e5 = (r >> 10) & 0x1Fu;
  unsigned int sgn = (u >> 8) & 0x80u;
  unsigned int out = ((r >> 7) & 7u) | ((e5 - 8u) << 3) | sgn;
  return (e5 < 9u) ? sgn : out;
}
__device__ __forceinline__ void macc8q(uint2 q, float* a, float w) {
  float v[8];
  dec8(q, v);
  #pragma unroll
  for (int k = 0; k < 8; ++k) a[k] += w * v[k];
}

// ---------------- graph preprocessing ----------------

__global__ void k_count(const int* __restrict__ dst, int* __restrict__ cnt,
                        int* __restrict__ rank) {
  int e = blockIdx.x * blockDim.x + threadIdx.x;
  if (e < NEDGE) rank[e] = atomicAdd(&cnt[dst[e]], 1);
}

__global__ void k_scan_sum(const int* __restrict__ cnt, int* __restrict__ sums,
                           float* __restrict__ dinv,
                           const unsigned short* __restrict__ xs,
                           const unsigned short* __restrict__ ws_,
                           int* __restrict__ flags) {
  __shared__ int sdata[256];
  int t = threadIdx.x, idx = blockIdx.x * 256 + t;
  int c = (idx < NODES) ? cnt[idx] : 0;
  if (idx < NODES) dinv[idx] = rsqrtf((float)c + 1.0f);   // +1 self loop
  sdata[t] = c;
  __syncthreads();
  for (int off = 128; off; off >>= 1) {
    if (t < off) sdata[t] += sdata[t + off];
    __syncthreads();
  }
  if (t == 0) sums[blockIdx.x] = sdata[0];
  if (blockIdx.x == 0 && t < 64) {
    const unsigned short* ptrs[2] = {xs, ws_};
    for (int k = 0; k < 2; ++k) {
      int bad = 0;
      for (int i = 0; i < 4; ++i) {
        float v = bf2f(ptrs[k][t * 4 + i]);
        float a = fabsf(v);
        if (!(a <= 1e4f) || (v != 0.f && a < 1e-10f)) bad++;   // NaN fails a<=1e4
      }
      for (int off = 32; off; off >>= 1) bad += __shfl_xor(bad, off);
      if (t == 0) flags[k] = (bad > 16) ? 1 : 0;   // 1 = fp32
    }
  }
}

// r21: scan_top folded in - every block redundantly scans sums[] (196 ints,
// L2-hot) and takes its own exclusive prefix. row_off[NODES] = NEDGE
// (structural: every edge counted exactly once).
__global__ void k_scan_final(const int* __restrict__ cnt, const int* __restrict__ sums,
                             int* __restrict__ row_off) {
  __shared__ int sdata[256];
  __shared__ int sboff;
  int t = threadIdx.x, idx = blockIdx.x * 256 + t;
  // top-level scan of block sums (same arithmetic as old k_scan_top)
  {
    int v = (t < NSB) ? sums[t] : 0;
    int cur = v;
    sdata[t] = cur; __syncthreads();
    for (int off = 1; off < 256; off <<= 1) {
      int add = (t >= off) ? sdata[t - off] : 0;
      __syncthreads();
      cur += add; sdata[t] = cur;
      __syncthreads();
    }
    if (t == blockIdx.x) sboff = cur - v;   // exclusive prefix at this block
    __syncthreads();
  }
  // per-element scan within this block
  int v = (idx < NODES) ? cnt[idx] : 0;
  int cur = v;
  sdata[t] = cur; __syncthreads();
  for (int off = 1; off < 256; off <<= 1) {
    int add = (t >= off) ? sdata[t - off] : 0;
    __syncthreads();
    cur += add; sdata[t] = cur;
    __syncthreads();
  }
  if (idx < NODES) row_off[idx] = sboff + cur - v;
  if (blockIdx.x == 0 && t == 0) row_off[NODES] = NEDGE;
}

#define FILL_BLOCKS (NEDGE / 256)   // 3125
#define QX_BLOCKS   (NODES * 128 / 8 / 256)   // 3125

// r12: no atomics; pos = row_off[d] + rank[e].
// r20: quant_x folded in as trailing blocks (flags valid by launch time).
__global__ void k_fill_prep(const int* __restrict__ src, const int* __restrict__ dst,
                            const int* __restrict__ row_off, const int* __restrict__ rank,
                            const float* __restrict__ dinv, unsigned int* __restrict__ edges,
                            const void* __restrict__ w1_0, const void* __restrict__ w1_1,
                            const void* __restrict__ w1_2, const void* __restrict__ w2_0,
                            const void* __restrict__ w2_1, const int* __restrict__ flags,
                            unsigned short* __restrict__ wt1, unsigned short* __restrict__ wt2,
                            const void* __restrict__ x, unsigned char* __restrict__ xq) {
  if (blockIdx.x < FILL_BLOCKS) {
    int e = blockIdx.x * 256 + threadIdx.x;
    int s = src[e], d = dst[e];
    int pos = row_off[d] + rank[e];
    float w = dinv[s] * dinv[d];
    _Float16 hw = (_Float16)w;
    edges[pos] = ((unsigned int)__builtin_bit_cast(unsigned short, hw) << 16)
               | (unsigned int)(s & 0xFFFF);
  } else if (blockIdx.x < FILL_BLOCKS + 312) {
    int fw = flags[1];
    int idx = (blockIdx.x - FILL_BLOCKS) * 256 + threadIdx.x;
    if (idx < 3 * 128 * 128) {
      int g = idx / 16384, r = idx % 16384;
      int n = r / 128, k = r % 128;
      const void* w = (g == 0) ? w1_0 : (g == 1) ? w1_1 : w1_2;
      wt1[idx] = f2bf(ldf(w, (size_t)k * 128 + n, fw));
    } else {
      int r = idx - 49152;   // 312*256 - 49152 = 30720 = 80*384 exactly
      int n = r / 384, k = r % 384;
      float v = (n < 40) ? ldf(w2_0, (size_t)k * 40 + n, fw)
                         : ldf(w2_1, (size_t)k * 40 + (n - 40), fw);
      wt2[r] = f2bf(v);
    }
  } else {
    // quant_x work (r10 kernel, folded)
    int f32 = flags[0];
    size_t i = ((size_t)(blockIdx.x - FILL_BLOCKS - 312) * 256 + threadIdx.x) * 8;
    float v[8];
    if (f32) {
      const float* xf = (const float*)x;
      #pragma unroll
      for (int k = 0; k < 8; ++k) v[k] = xf[i + k];
    } else {
      uint4 q = *(const uint4*)((const unsigned short*)x + i);
      v[0] = bf2f((unsigned short)(q.x & 0xFFFF));
      v[1] = bf2f((unsigned short)(q.x >> 16));
      v[2] = bf2f((unsigned short)(q.y & 0xFFFF));
      v[3] = bf2f((unsigned short)(q.y >> 16));
      v[4] = bf2f((unsigned short)(q.z & 0xFFFF));
      v[5] = bf2f((unsigned short)(q.z >> 16));
      v[6] = bf2f((unsigned short)(q.w & 0xFFFF));
      v[7] = bf2f((unsigned short)(q.w >> 16));
    }
    uint2 o;
    o.x = fp8e(v[0]) | (fp8e(v[1]) << 8) | (fp8e(v[2]) << 16) | (fp8e(v[3]) << 24);
    o.y = fp8e(v[4]) | (fp8e(v[5]) << 8) | (fp8e(v[6]) << 16) | (fp8e(v[7]) << 24);
    *(uint2*)(xq + i) = o;
  }
}

__device__ __forceinline__ void unpack_edge(unsigned int e, int& s, float& w) {
  s = (int)(e & 0xFFFFu);
  w = (float)__builtin_bit_cast(_Float16, (unsigned short)(e >> 16));
}

// ---------------- 128-wide propagate, fp8 gather ----------------
// r18: edge-word prefetch (1-pair lookahead); accumulation order identical
// to r16 (same slot/pair pairing into acc/acc2).
__global__ __launch_bounds__(256) void k_prop128(
    const unsigned char* __restrict__ inq, void* __restrict__ outp,
    const int* __restrict__ row_off, const unsigned int* __restrict__ edges,
    const float* __restrict__ dinv, int out_fp8) {
  int v = blockIdx.x * 4 + (threadIdx.x >> 6);
  if (v >= NODES) return;
  int lane = threadIdx.x & 63;
  int rb = row_off[v], re = row_off[v + 1];
  float dv = dinv[v];
  float wsw = dv * dv;
  int slot = lane >> 4, fl = lane & 15;
  float acc[8], acc2[8];
  {
    uint2 q = *(const uint2*)(inq + (size_t)v * 128 + fl * 8);
    float sw = (slot == 0) ? wsw : 0.f;
    float v8[8];
    dec8(q, v8);
    #pragma unroll
    for (int k = 0; k < 8; ++k) { acc[k] = sw * v8[k]; acc2[k] = 0.f; }
  }
  int j = rb + slot;
  if (j + 4 < re) {
    unsigned e1 = edges[j], e2 = edges[j + 4];
    j += 8;
    for (; j + 4 < re; j += 8) {
      unsigned n1 = edges[j], n2 = edges[j + 4];   // prefetch next pair
      int s1; float w1; unpack_edge(e1, s1, w1);
      int s2; float w2; unpack_edge(e2, s2, w2);
      uint2 q1 = *(const uint2*)(inq + (size_t)s1 * 128 + fl * 8);
      uint2 q2 = *(const uint2*)(inq + (size_t)s2 * 128 + fl * 8);
      macc8q(q1, acc, w1);
      macc8q(q2, acc2, w2);
      e1 = n1; e2 = n2;
    }
    // final prefetched pair
    int s1; float w1; unpack_edge(e1, s1, w1);
    int s2; float w2; unpack_edge(e2, s2, w2);
    uint2 q1 = *(const uint2*)(inq + (size_t)s1 * 128 + fl * 8);
    uint2 q2 = *(const uint2*)(inq + (size_t)s2 * 128 + fl * 8);
    macc8q(q1, acc, w1);
    macc8q(q2, acc2, w2);
  }
  if (j < re) {
    int s; float w; unpack_edge(edges[j], s, w);
    uint2 q = *(const uint2*)(inq + (size_t)s * 128 + fl * 8);
    macc8q(q, acc, w);
  }
  #pragma unroll
  for (int k = 0; k < 8; ++k) acc[k] += acc2[k];
  #pragma unroll
  for (int k = 0; k < 8; ++k) {
    acc[k] += __shfl_xor(acc[k], 32);
    acc[k] += __shfl_xor(acc[k], 16);
  }
  if (slot == 0) {
    #pragma unroll
    for (int k = 0; k < 8; ++k) acc[k] = fin(acc[k]);
    if (out_fp8) {
      uint2 o;
      o.x = fp8e(acc[0]) | (fp8e(acc[1]) << 8) | (fp8e(acc[2]) << 16) | (fp8e(acc[3]) << 24);
      o.y = fp8e(acc[4]) | (fp8e(acc[5]) << 8) | (fp8e(acc[6]) << 16) | (fp8e(acc[7]) << 24);
      *(uint2*)((unsigned char*)outp + (size_t)v * 128 + fl * 8) = o;
    } else {
      uint4 o = pack8(acc);
      *(uint4*)((unsigned short*)outp + (size_t)v * 128 + fl * 8) = o;
    }
  }
}

// ---------------- fused conv1+conv2 (r16/r12 structure; r13 epilogue) ----
// lW/lW2/lA LDS staging, 3 barriers/g. z1 written fp8 directly.
__global__ __launch_bounds__(256) void k_gemm_fused(
    const void* __restrict__ x, const unsigned char* __restrict__ x1q,
    const unsigned short* __restrict__ x2, const unsigned short* __restrict__ wt1,
    const unsigned short* __restrict__ wt2,
    const unsigned short* __restrict__ b0, const unsigned short* __restrict__ b1,
    const unsigned short* __restrict__ b2, void* __restrict__ outp,
    unsigned char* __restrict__ z1q, const int* __restrict__ flags) {
  __shared__ unsigned short lA[64 * 136];    // h tile only
  __shared__ unsigned short lW[128 * 136];   // W1_g [n][k]
  __shared__ unsigned short lW2[80 * 136];   // W2 slice [n][kk]
  int f32x = flags[0];
  int m0 = blockIdx.x * 64;
  int t = threadIdx.x;
  int wave = t >> 6, lane = t & 63;
  int lr = lane & 15, lq = lane >> 4;
  int wr = (wave >> 1) * 32, wc = (wave & 1) * 64;
  floatx4 zacc[5] = {};

  for (int g = 0; g < 3; ++g) {
    const unsigned short* Ab = (g == 0) ? (const unsigned short*)x : x2;
    const unsigned short* W = wt1 + g * 16384;
    const unsigned short* bias = (g == 0) ? b0 : (g == 1) ? b1 : b2;
    __syncthreads();   // prior z-phase lW2/lA reads complete
    for (int i = 0; i < 8; ++i) {            // W1: 128 x 16 chunks
      int idx = t + i * 256;
      int row = idx >> 4, c16 = idx & 15;
      *(uint4*)(&lW[row * 136 + c16 * 8]) =
          *(const uint4*)(W + row * 128 + c16 * 8);
    }
    for (int i = 0; i < 5; ++i) {            // W2 slice: 80 x 16
      int idx = t + i * 256;
      int n = idx >> 4, c16 = idx & 15;
      *(uint4*)(&lW2[n * 136 + c16 * 8]) =
          *(const uint4*)(wt2 + n * 384 + g * 128 + c16 * 8);
    }
    __syncthreads();

    // h-phase: A fragments straight from global
    floatx4 acc[2][4] = {};
    for (int ks = 0; ks < 4; ++ks) {
      int k0 = ks * 32 + lq * 8;
      bf16x8 af[2], bfr[4];
      for (int i = 0; i < 2; ++i) {
        int gr = m0 + wr + i * 16 + lr;
        if (gr < NODES) {
          if (g == 1) {
            uint2 qq = *(const uint2*)(x1q + (size_t)gr * 128 + k0);
            float tv[8];
            dec8(qq, tv);
            uint4 t4 = pack8(tv);
            af[i] = __builtin_bit_cast(bf16x8, t4);
          } else if (g == 0 && f32x) {
            uint4 t4 = pack8((const float*)x + (size_t)gr * 128 + k0);
            af[i] = __builtin_bit_cast(bf16x8, t4);
          } else {
            af[i] = *(const bf16x8*)(Ab + (size_t)gr * 128 + k0);
          }
        } else {
          uint4 zz = {0, 0, 0, 0};
          af[i] = __builtin_bit_cast(bf16x8, zz);
        }
      }
      for (int j = 0; j < 4; ++j)
        bfr[j] = *(const bf16x8*)(&lW[(wc + j * 16 + lr) * 136 + k0]);
      for (int i = 0; i < 2; ++i)
        for (int j = 0; j < 4; ++j)
          acc[i][j] = __builtin_amdgcn_mfma_f32_16x16x32_bf16(af[i], bfr[j], acc[i][j], 0, 0, 0);
    }
    // h -> LDS (lA free: last reads were before top-of-loop barrier)
    for (int i = 0; i < 2; ++i) {
      int rloc = wr + i * 16 + lq * 4;
      for (int j = 0; j < 4; ++j) {
        int col = wc + j * 16 + lr;
        float bv = bf2f(bias[col]);
        for (int r = 0; r < 4; ++r) {
          float val = acc[i][j][r] + bv;
          val = val > 0.f ? val : 0.f;       // relu (squashes NaN too)
          lA[(rloc + r) * 136 + col] = f2bf(val);
        }
      }
    }
    __syncthreads();
    // z-phase
    for (int ks = 0; ks < 4; ++ks) {
      int k0 = ks * 32 + lq * 8;
      bf16x8 ah = *(const bf16x8*)(&lA[(wave * 16 + lr) * 136 + k0]);
      bf16x8 bw[5];
      for (int j = 0; j < 5; ++j)
        bw[j] = *(const bf16x8*)(&lW2[(j * 16 + lr) * 136 + k0]);
      for (int j = 0; j < 5; ++j)
        zacc[j] = __builtin_amdgcn_mfma_f32_16x16x32_bf16(ah, bw[j], zacc[j], 0, 0, 0);
    }
  }
  int rbase = m0 + wave * 16 + lq * 4;
  for (int j = 0; j < 5; ++j) {
    int col = j * 16 + lr;
    for (int r = 0; r < 4; ++r) {
      int gr = rbase + r;
      if (gr < NODES) {
        float vv = zacc[j][r];
        if (col < 40) {
          if (f32x) ((float*)outp)[(size_t)gr * 80 + col] = vv;
          else ((unsigned short*)outp)[(size_t)gr * 80 + col] = f2bf(vv);
        } else {
          z1q[(size_t)gr * 40 + (col - 40)] = (unsigned char)fp8e(vv);
        }
      }
    }
  }
}

// ---------------- fused 40-d propagate + bias + log_softmax ----------------
// r13 fp8 z1 path + r18 edge-word prefetch (order identical to r16).
__global__ __launch_bounds__(256) void k_prop40_softmax(
    const unsigned char* __restrict__ z1q, const unsigned short* __restrict__ b2_0,
    const unsigned short* __restrict__ b2_1, const int* __restrict__ row_off,
    const unsigned int* __restrict__ edges, const float* __restrict__ dinv,
    void* __restrict__ outp, const int* __restrict__ flags) {
  int f32o = flags[0];
  int v = blockIdx.x * 4 + (threadIdx.x >> 6);
  if (v >= NODES) return;
  int lane = threadIdx.x & 63;
  int slot = lane >> 5, fl = lane & 31;
  bool gact = fl < 20;
  int fo = gact ? fl * 2 : 0;
  int rb = row_off[v], re = row_off[v + 1];
  float dv = dinv[v];
  float wsw = dv * dv;
  float ax = 0.f, ay = 0.f, bx = 0.f, by = 0.f;
  if (slot == 0) {
    unsigned int p = *(const unsigned short*)(z1q + (size_t)v * 40 + fo);
    floatx2 d = dec2(p);
    ax = wsw * d[0];
    ay = wsw * d[1];
  }
  int j = rb + slot;
  if (j + 2 < re) {
    unsigned e1 = edges[j], e2 = edges[j + 2];
    j += 4;
    for (; j + 2 < re; j += 4) {
      unsigned n1 = edges[j], n2 = edges[j + 2];   // prefetch next pair
      int s1; float w1; unpack_edge(e1, s1, w1);
      int s2; float w2; unpack_edge(e2, s2, w2);
      unsigned int q1 = *(const unsigned short*)(z1q + (size_t)s1 * 40 + fo);
      unsigned int q2 = *(const unsigned short*)(z1q + (size_t)s2 * 40 + fo);
      floatx2 d1 = dec2(q1);
      floatx2 d2 = dec2(q2);
      ax += w1 * d1[0];
      ay += w1 * d1[1];
      bx += w2 * d2[0];
      by += w2 * d2[1];
      e1 = n1; e2 = n2;
    }
    // final prefetched pair
    int s1; float w1; unpack_edge(e1, s1, w1);
    int s2; float w2; unpack_edge(e2, s2, w2);
    unsigned int q1 = *(const unsigned short*)(z1q + (size_t)s1 * 40 + fo);
    unsigned int q2 = *(const unsigned short*)(z1q + (size_t)s2 * 40 + fo);
    floatx2 d1 = dec2(q1);
    floatx2 d2 = dec2(q2);
    ax += w1 * d1[0];
    ay += w1 * d1[1];
    bx += w2 * d2[0];
    by += w2 * d2[1];
  }
  if (j < re) {
    int s; float w; unpack_edge(edges[j], s, w);
    unsigned int q = *(const unsigned short*)(z1q + (size_t)s * 40 + fo);
    floatx2 d = dec2(q);
    ax += w * d[0];
    ay += w * d[1];
  }
  ax += bx; ay += by;
  ax += __shfl_xor(ax, 32);
  ay += __shfl_xor(ay, 32);
  bool act = lane < 20;
  float l0x = 0.f, l0y = 0.f, l1x = 0.f, l1y = 0.f;
  if (act) {
    l0x = fin(ldf(outp, (size_t)v * 80 + fo, f32o)     + bf2f(b2_0[fo]));
    l0y = fin(ldf(outp, (size_t)v * 80 + fo + 1, f32o) + bf2f(b2_0[fo + 1]));
    l1x = fin(ax + bf2f(b2_1[fo]));
    l1y = fin(ay + bf2f(b2_1[fo + 1]));
  }
  float m = act ? fmaxf(fmaxf(l0x, l0y), fmaxf(l1x, l1y)) : -INFINITY;
  for (int off = 32; off; off >>= 1) m = fmaxf(m, __shfl_xor(m, off));
  float s = act ? (expf(l0x - m) + expf(l0y - m) + expf(l1x - m) + expf(l1y - m)) : 0.f;
  for (int off = 32; off; off >>= 1) s += __shfl_xor(s, off);
  float lse = m + logf(s);
  if (act) {
    if (f32o) {
      float* of = (float*)outp;
      of[(size_t)v * 80 + fo]          = l0x - lse;
      of[(size_t)v * 80 + fo + 1]      = l0y - lse;
      of[(size_t)v * 80 + 40 + fo]     = l1x - lse;
      of[(size_t)v * 80 + 40 + fo + 1] = l1y - lse;
    } else {
      unsigned short* ob = (unsigned short*)outp;
      unsigned int o0 = ((unsigned int)f2bf(l0y - lse) << 16) | f2bf(l0x - lse);
      unsigned int o1 = ((unsigned int)f2bf(l1y - lse) << 16) | f2bf(l1x - lse);
      *(unsigned int*)(ob + (size_t)v * 80 + fo) = o0;
      *(unsigned int*)(ob + (size_t)v * 80 + 40 + fo) = o1;
    }
  }
}

// sentinel: ws too small — encode its MB count into the output
__global__ void k_sentinel(unsigned short* o, int n, float val) {
  int i = blockIdx.x * blockDim.x + threadIdx.x;
  if (i < n) o[i] = f2bf(val);
}

// ---------------- host ----------------

static inline size_t al256(size_t x) { return (x + 255) & ~(size_t)255; }

extern "C" void kernel_launch(void* const* d_in, const int* in_sizes, int n_in,
                              void* d_out, int out_size, void* d_ws, size_t ws_size,
                              hipStream_t stream) {
  const void* x    = d_in[0];
  const int*  ei   = (const int*)d_in[1];
  const void* w1_0 = d_in[2];
  const unsigned short* b1_0 = (const unsigned short*)d_in[3];
  const void* w1_1 = d_in[4];
  const unsigned short* b1_1 = (const unsigned short*)d_in[5];
  const void* w1_2 = d_in[6];
  const unsigned short* b1_2 = (const unsigned short*)d_in[7];
  const void* w2_0 = d_in[8];
  const unsigned short* b2_0 = (const unsigned short*)d_in[9];
  const void* w2_1 = d_in[10];
  const unsigned short* b2_1 = (const unsigned short*)d_in[11];
  const int* srcv = ei;
  const int* dstv = ei + NEDGE;

  // ws layout: same 33.8 MB total as r4-r20. z1 bf16 slot unused (layout
  // stability). rank[] AND z1q alias the x2v slot at disjoint times:
  // rank (count..fill) -> x2v (prop128-pass2..gemm A-read) -> z1q
  // (gemm epilogue..prop40). boff slot now unused (scan_top folded).
  char* p = (char*)d_ws;
  int*   flags   = (int*)p;               p += al256(2 * 4);
  int*   row_off = (int*)p;               p += al256((NODES + 1) * 4);
  float* dinv    = (float*)p;             p += al256(NODES * 4);
  unsigned int* edges = (unsigned int*)p; p += al256((size_t)NEDGE * 4);
  unsigned short* wt1 = (unsigned short*)p; p += al256(3 * 128 * 128 * 2);
  unsigned short* wt2 = (unsigned short*)p; p += al256(80 * 384 * 2);
  unsigned char* xq  = (unsigned char*)p; p += al256((size_t)NODES * 128);
  unsigned char* x1q = (unsigned char*)p; p += al256((size_t)NODES * 128);
  unsigned short* x2v = (unsigned short*)p; p += al256((size_t)NODES * 128 * 2);
  unsigned short* z1 = (unsigned short*)p; p += al256((size_t)NODES * 40 * 2);
  int*   cnt     = (int*)p;               p += al256(NODES * 4);
  int*   cursor  = (int*)p;               p += al256(NODES * 4);
  int*   sums    = (int*)p;               p += al256(NSB * 4);
  int*   boff    = (int*)p;               p += al256(NSB * 4);
  size_t need = (size_t)(p - (char*)d_ws);
  int* rank = (int*)x2v;                 // early alias of x2v slot
  unsigned char* z1q = (unsigned char*)x2v;  // late alias (x2v dead post-gemm A-read)
  (void)cursor; (void)z1; (void)boff;

  if (ws_size < need) {
    float val = -1000.f - (float)(ws_size >> 20);
    k_sentinel<<<(out_size + 255) / 256, 256, 0, stream>>>(
        (unsigned short*)d_out, out_size, val);
    return;
  }

  hipMemsetAsync(cnt, 0, al256(NODES * 4) + NODES * 4, stream);
  k_count<<<NEDGE / 256, 256, 0, stream>>>(dstv, cnt, rank);
  k_scan_sum<<<NSB, 256, 0, stream>>>(cnt, sums, dinv,
                                      (const unsigned short*)x,
                                      (const unsigned short*)w1_0, flags);
  k_scan_final<<<NSB, 256, 0, stream>>>(cnt, sums, row_off);
  k_fill_prep<<<FILL_BLOCKS + 312 + QX_BLOCKS, 256, 0, stream>>>(
      srcv, dstv, row_off, rank, dinv, edges,
      w1_0, w1_1, w1_2, w2_0, w2_1, flags, wt1, wt2, x, xq);
  k_prop128<<<NODES / 4, 256, 0, stream>>>(xq, x1q, row_off, edges, dinv, 1);
  k_prop128<<<NODES / 4, 256, 0, stream>>>(x1q, x2v, row_off, edges, dinv, 0);
  k_gemm_fused<<<(NODES + 63) / 64, 256, 0, stream>>>(x, x1q, x2v, wt1, wt2,
                                                      b1_0, b1_1, b1_2, d_out, z1q, flags);
  k_prop40_softmax<<<NODES / 4, 256, 0, stream>>>(z1q, b2_0, b2_1, row_off, edges,
                                                  dinv, d_out, flags);
}